// Round 10
// baseline (474.308 us; speedup 1.0000x reference)
//
#include <hip/hip_runtime.h>

// Local context aggregation (DGCNN edge-conv style), MI355X.
// Pipeline:
//   k_feat : per-point transforms yF1=A1f·x, yFc=(A2f-A1f)·x, yD1, yDc + xneg=-0.5|x|^2
//   k_prep : split-bf16 tables hl[n][hi96|lo96] + transposed xT[n][96] f32
//   k_dist : FUSED MFMA score + per-half top-24. 2048 blocks x 256 thr (4 waves).
//            launch_bounds (256,8): R9 showed runtime occupancy tracks the min-waves
//            hint (R8 hint6->55%, R9 hint4->40%) while VGPR already fits the 64-reg
//            8-wave tier. Insert via v_med3_u32 (12 VALU/score vs 23; R7's idea, minus
//            R7's spill-inducing launch bounds). Immediate-offset fragment loads.
//   k_sel  : per row, f64-score the 48 union candidates (2 lanes/cand), exact top-20.
//   k_stats/k_bn/k_out : BN over edge norms + directional leaky act + mean over k.
//            XCD-swizzled (b=blk&3) so each XCD L2 caches one batch's gather tables.
// ws usage: ~42 MB fixed.

namespace {
constexpr int BB = 4;
constexpr int NN = 4096;
constexpr int KK = 20;
constexpr int CC = 96;      // 32 features x 3 dims
constexpr int OO = 32;
constexpr int PTS = BB * NN;
constexpr int LT = 12;      // per-class top list depth (class = 128 cands)
constexpr int TCAND = 24;   // per-half candidates kept
constexpr int NENT = 16 * LT;     // entries per row: 4 waves x 4 kl x 12 = 192
constexpr int NENT_PAD = 196;     // padded row stride (words)
constexpr int RSTRIDE = 100;
}

using bf16x8 = __attribute__((ext_vector_type(8))) short;
using f32x4 = __attribute__((ext_vector_type(4))) float;

__device__ __forceinline__ unsigned short f2bf(float f) {
  unsigned u = __float_as_uint(f);
  return (unsigned short)((u + 0x7fff + ((u >> 16) & 1)) >> 16);
}
__device__ __forceinline__ float bf2f(unsigned short b) {
  return __uint_as_float((unsigned)b << 16);
}
__device__ __forceinline__ unsigned umax32(unsigned a, unsigned b) { return a > b ? a : b; }
__device__ __forceinline__ unsigned med3u(unsigned a, unsigned b, unsigned c) {
  unsigned d;
  asm("v_med3_u32 %0, %1, %2, %3" : "=v"(d) : "v"(a), "v"(b), "v"(c));
  return d;
}

// ---------------- kernel 1: per-point transforms + xneg ----------------
__global__ __launch_bounds__(256) void k_feat(
    const float* __restrict__ x, const float* __restrict__ Wf,
    const float* __restrict__ Wd,
    float* __restrict__ yF1, float* __restrict__ yFc,
    float* __restrict__ yD1, float* __restrict__ yDc,
    float* __restrict__ xneg) {
  __shared__ float sW[4][32][32];
  __shared__ float sx[8][RSTRIDE];
  const int t = threadIdx.x;
  for (int i = t; i < 2048; i += 256) {
    int o = i & 31, f = (i >> 5) & 31, which = i >> 10;
    const float* W = which ? Wd : Wf;
    float a1 = W[o * 64 + f], a2 = W[o * 64 + 32 + f];
    sW[which * 2 + 0][f][o] = a1;
    sW[which * 2 + 1][f][o] = a2 - a1;
  }
  const int b = blockIdx.x >> 9;
  const int n0 = (blockIdx.x & 511) * 8;
  for (int i = t; i < 8 * CC; i += 256) {
    int pl = i & 7, c = i >> 3;
    sx[pl][c] = x[((size_t)b * CC + c) * NN + n0 + pl];
  }
  __syncthreads();
  const int o = t & 31, pl = t >> 5;
  float aF1[3] = {0.f, 0.f, 0.f}, aFc[3] = {0.f, 0.f, 0.f};
  float aD1[3] = {0.f, 0.f, 0.f}, aDc[3] = {0.f, 0.f, 0.f};
#pragma unroll
  for (int f = 0; f < 32; ++f) {
    float w0 = sW[0][f][o], w1 = sW[1][f][o];
    float w2 = sW[2][f][o], w3 = sW[3][f][o];
#pragma unroll
    for (int dd = 0; dd < 3; ++dd) {
      float v = sx[pl][f * 3 + dd];
      aF1[dd] = fmaf(w0, v, aF1[dd]);
      aFc[dd] = fmaf(w1, v, aFc[dd]);
      aD1[dd] = fmaf(w2, v, aD1[dd]);
      aDc[dd] = fmaf(w3, v, aDc[dd]);
    }
  }
  const size_t pt = (size_t)(b * NN + n0 + pl) * CC + o * 3;
#pragma unroll
  for (int dd = 0; dd < 3; ++dd) {
    yF1[pt + dd] = aF1[dd]; yFc[pt + dd] = aFc[dd];
    yD1[pt + dd] = aD1[dd]; yDc[pt + dd] = aDc[dd];
  }
  float part = 0.f;
#pragma unroll
  for (int dd = 0; dd < 3; ++dd) { float v = sx[pl][o * 3 + dd]; part += v * v; }
#pragma unroll
  for (int off = 16; off >= 1; off >>= 1) part += __shfl_down(part, off, 32);
  if (o == 0) xneg[b * NN + n0 + pl] = -0.5f * part;
}

// ---------------- kernel 1b: split-bf16 + transposed tables ----------------
__global__ __launch_bounds__(256) void k_prep(
    const float* __restrict__ x, unsigned short* __restrict__ hl,
    float* __restrict__ xT) {
  __shared__ float tile[CC][65];
  const int t = threadIdx.x;
  const int b = blockIdx.x >> 6;             // 64 blocks per batch
  const int n0 = (blockIdx.x & 63) * 64;
#pragma unroll
  for (int i = 0; i < 24; ++i) {
    int v = i * 256 + t;
    int c = v >> 6, nn = v & 63;
    tile[c][nn] = x[((size_t)b * CC + c) * NN + n0 + nn];
  }
  __syncthreads();
  // hl rows: [hi 96 | lo 96] bf16, written as 24 x 16B chunks per row
#pragma unroll
  for (int i = 0; i < 6; ++i) {
    int v = i * 256 + t;                    // 0..1535 over 64 rows x 24 chunks
    int row = v / 24, k8 = v % 24;
    unsigned hb[4];
    if (k8 < 12) {
      int c0 = k8 * 8;
#pragma unroll
      for (int j = 0; j < 4; ++j) {
        unsigned short l16 = f2bf(tile[c0 + 2 * j][row]);
        unsigned short h16 = f2bf(tile[c0 + 2 * j + 1][row]);
        hb[j] = (unsigned)l16 | ((unsigned)h16 << 16);
      }
    } else {
      int c0 = (k8 - 12) * 8;
#pragma unroll
      for (int j = 0; j < 4; ++j) {
        float f0 = tile[c0 + 2 * j][row], f1 = tile[c0 + 2 * j + 1][row];
        unsigned short h0 = f2bf(f0), h1 = f2bf(f1);
        unsigned short l0 = f2bf(f0 - bf2f(h0)), l1 = f2bf(f1 - bf2f(h1));
        hb[j] = (unsigned)l0 | ((unsigned)l1 << 16);
      }
    }
    *(uint4*)(hl + (size_t)(b * NN + n0 + row) * 192 + k8 * 8) =
        make_uint4(hb[0], hb[1], hb[2], hb[3]);
  }
  // xT rows: 96 f32 contiguous per point
#pragma unroll
  for (int i = 0; i < 6; ++i) {
    int v = i * 256 + t;
    int row = v / 24, q = v % 24;
    float4 o4;
    o4.x = tile[q * 4 + 0][row]; o4.y = tile[q * 4 + 1][row];
    o4.z = tile[q * 4 + 2][row]; o4.w = tile[q * 4 + 3][row];
    *(float4*)(xT + (size_t)(b * NN + n0 + row) * CC + q * 4) = o4;
  }
}

// ---------------- kernel 2: FUSED MFMA score + per-half top-24 ----------------
// 2048 blocks x 256 thr (4 waves). xcd=wg&7: b=xcd&3, half=xcd>>2. q=wg>>3 -> 16 rows.
// Wave w scans [half*2048 + w*512, +512) over 8 m-tiles of 64.
// key = monotone(score)[31:12] | class[10:7] | (127-local)[6:0]  (unique in block).
__global__ __launch_bounds__(256, 8) void k_dist(
    const unsigned short* __restrict__ hl, const float* __restrict__ xneg,
    unsigned* __restrict__ candbuf) {
  __shared__ unsigned sEnt[16][NENT_PAD];
  const int t = threadIdx.x, lane = t & 63, w = t >> 6;
  const int wg = blockIdx.x;
  const int xcd = wg & 7;
  const int b = xcd & 3;
  const int half = xcd >> 2;
  const int nbase = (wg >> 3) << 4;          // 0..4080, step 16
  const int hoff = half * 2048;
  const int coff = hoff + w * 512;           // this wave's candidate range
  const unsigned short* hb = hl + (size_t)b * NN * 192;
  const int kl = lane >> 4, pr = lane & 15;
  const int cls = w * 4 + kl;                // 0..15
  const unsigned clsbase = (unsigned)(cls << 7);

  // resident operand-B fragments: the block's 16 query rows (col axis)
  bf16x8 rHf[3], rLf[3];
#pragma unroll
  for (int kb = 0; kb < 3; ++kb) {
    const unsigned short* p = hb + (size_t)(nbase + pr) * 192 + (kb * 4 + kl) * 8;
    rHf[kb] = *(const bf16x8*)p;
    rLf[kb] = *(const bf16x8*)(p + 96);
  }

  unsigned ls[LT];
#pragma unroll
  for (int j = 0; j < LT; ++j) ls[j] = 0u;   // 0 == -inf key

  // strength-reduced bases: all inner-loop loads use compile-time immediate offsets
  const unsigned short* pw = hb + ((size_t)coff + pr) * 192 + (size_t)kl * 8;
  const float* px = xneg + (size_t)b * NN + coff + kl * 4;

  for (int mt = 0; mt < 8; ++mt) {
    const unsigned tagbase = clsbase | (unsigned)(127 - mt * 16);
#pragma unroll
    for (int ca = 0; ca < 4; ++ca) {
      const unsigned short* pc = pw + ca * 3072;      // 16 rows * 192 shorts
      f32x4 acc = *(const f32x4*)(px + ca * 16);      // -0.5*|xm|^2 preloaded
      bf16x8 h0 = *(const bf16x8*)(pc);
      bf16x8 l0 = *(const bf16x8*)(pc + 96);
      bf16x8 h1 = *(const bf16x8*)(pc + 32);
      bf16x8 l1 = *(const bf16x8*)(pc + 128);
      bf16x8 h2 = *(const bf16x8*)(pc + 64);
      bf16x8 l2 = *(const bf16x8*)(pc + 160);
      // (candH+candL)·(rowH+rowL) ~= cH·rH + cL·rH + cH·rL  (lo·lo ~2^-16)
      acc = __builtin_amdgcn_mfma_f32_16x16x32_bf16(h0, rHf[0], acc, 0, 0, 0);
      acc = __builtin_amdgcn_mfma_f32_16x16x32_bf16(l0, rHf[0], acc, 0, 0, 0);
      acc = __builtin_amdgcn_mfma_f32_16x16x32_bf16(h0, rLf[0], acc, 0, 0, 0);
      acc = __builtin_amdgcn_mfma_f32_16x16x32_bf16(h1, rHf[1], acc, 0, 0, 0);
      acc = __builtin_amdgcn_mfma_f32_16x16x32_bf16(l1, rHf[1], acc, 0, 0, 0);
      acc = __builtin_amdgcn_mfma_f32_16x16x32_bf16(h1, rLf[1], acc, 0, 0, 0);
      acc = __builtin_amdgcn_mfma_f32_16x16x32_bf16(h2, rHf[2], acc, 0, 0, 0);
      acc = __builtin_amdgcn_mfma_f32_16x16x32_bf16(l2, rHf[2], acc, 0, 0, 0);
      acc = __builtin_amdgcn_mfma_f32_16x16x32_bf16(h2, rLf[2], acc, 0, 0, 0);
      // C/D: col(lane&15)=query row; row((lane>>4)*4+r)=candidate offset.
      const unsigned tag = tagbase - (unsigned)(ca * 4);
#pragma unroll
      for (int r = 0; r < 4; ++r) {
        unsigned sb = __float_as_uint(acc[r]);
        sb ^= ((unsigned)((int)sb >> 31)) | 0x80000000u;
        unsigned key = (sb & 0xFFFFF000u) | (tag - (unsigned)r);
        // in-place parallel sorted-desc insert via med3 (descending j:
        // reads ls[j-1] (old) and ls[j] (old) -> 1 inst/stage)
#pragma unroll
        for (int j = LT - 1; j >= 1; --j)
          ls[j] = med3u(ls[j - 1], ls[j], key);
        ls[0] = umax32(ls[0], key);
      }
    }
    pw += 64 * 192;
    px += 64;
  }
  // dump per-lane sorted key lists: row pr, entries [cls*12 .. +12)
  {
    unsigned* dst = &sEnt[pr][cls * LT];
    *(uint4*)(dst + 0) = make_uint4(ls[0], ls[1], ls[2], ls[3]);
    *(uint4*)(dst + 4) = make_uint4(ls[4], ls[5], ls[6], ls[7]);
    *(uint4*)(dst + 8) = make_uint4(ls[8], ls[9], ls[10], ls[11]);
  }
  __syncthreads();

  // rank-count merge: wave w handles rows w*4..w*4+3; lane owns entries {lane+64c}.
  // Keys unique -> ranks 0..191 a permutation -> all 24 candbuf slots written.
#pragma unroll
  for (int rr = 0; rr < 4; ++rr) {
    const int row = w * 4 + rr;
    unsigned mine[3]; int rk[3] = {0, 0, 0};
#pragma unroll
    for (int c = 0; c < 3; ++c) mine[c] = sEnt[row][lane + 64 * c];
    for (int i4 = 0; i4 < NENT / 4; ++i4) {
      uint4 e = *(const uint4*)&sEnt[row][i4 * 4];
#pragma unroll
      for (int c = 0; c < 3; ++c) {
        rk[c] += (e.x > mine[c]) ? 1 : 0;
        rk[c] += (e.y > mine[c]) ? 1 : 0;
        rk[c] += (e.z > mine[c]) ? 1 : 0;
        rk[c] += (e.w > mine[c]) ? 1 : 0;
      }
    }
#pragma unroll
    for (int c = 0; c < 3; ++c) {
      if (rk[c] < TCAND) {
        unsigned low = mine[c] & 0x7FFu;
        int kcls = (int)(low >> 7);
        int loc = 127 - (int)(low & 127u);
        unsigned id = (unsigned)(hoff + (kcls >> 2) * 512 + (loc >> 4) * 64 +
                                 ((loc >> 2) & 3) * 16 + (kcls & 3) * 4 + (loc & 3));
        candbuf[(size_t)(b * NN + nbase + row) * 48 + half * 24 + rk[c]] = id;
      }
    }
  }
}

// ---------------- kernel 2b: exact f64 top-20 from 48 union candidates ----------------
// One wave per row. 2 lanes per candidate (48 dims each); u64 keys with id tie-break
// (np top_k: ties -> lower index). Ranks unique -> all 20 slots written.
__global__ __launch_bounds__(256) void k_sel(
    const unsigned* __restrict__ candbuf, const float* __restrict__ xT,
    int* __restrict__ idxout) {
  const int t = threadIdx.x, lane = t & 63, w = t >> 6;
  const int row = blockIdx.x * 4 + w;        // 0..16383
  const int b = row >> 12, n = row & (NN - 1);
  const unsigned* cp = candbuf + (size_t)row * 48;
  const int hf = lane & 1;
  unsigned long long k0, k1; int c0, c1;
#pragma unroll
  for (int pass = 0; pass < 2; ++pass) {
    const int ci = pass * 24 + ((lane < 48) ? (lane >> 1) : 23);
    const int mycand = (int)cp[ci];
    const float* xm = xT + ((size_t)b * NN + mycand) * CC + hf * 48;
    const float* xr = xT + ((size_t)b * NN + n) * CC + hf * 48;
    double dot = 0.0, m2 = 0.0;
#pragma unroll 4
    for (int j = 0; j < 12; ++j) {
      float4 a = *(const float4*)&xm[j * 4];
      float4 q = *(const float4*)&xr[j * 4];
      dot = fma((double)q.x, (double)a.x, dot); m2 = fma((double)a.x, (double)a.x, m2);
      dot = fma((double)q.y, (double)a.y, dot); m2 = fma((double)a.y, (double)a.y, m2);
      dot = fma((double)q.z, (double)a.z, dot); m2 = fma((double)a.z, (double)a.z, m2);
      dot = fma((double)q.w, (double)a.w, dot); m2 = fma((double)a.w, (double)a.w, m2);
    }
    dot += __shfl_xor(dot, 1);
    m2 += __shfl_xor(m2, 1);
    double sc = 2.0 * dot - m2;
    unsigned long long bits = (unsigned long long)__double_as_longlong(sc);
    bits ^= ((unsigned long long)((long long)bits >> 63)) | 0x8000000000000000ull;
    unsigned long long key = (bits & ~0xFFFull) | (unsigned long long)(4095 - mycand);
    if (pass == 0) { k0 = key; c0 = mycand; } else { k1 = key; c1 = mycand; }
  }
  int r0 = 0, r1 = 0;
#pragma unroll
  for (int j = 0; j < 24; ++j) {
    unsigned long long a = __shfl(k0, j * 2);
    unsigned long long bb = __shfl(k1, j * 2);
    r0 += (a > k0) ? 1 : 0; r0 += (bb > k0) ? 1 : 0;
    r1 += (a > k1) ? 1 : 0; r1 += (bb > k1) ? 1 : 0;
  }
  if (lane < 48 && hf == 0) {
    if (r0 < KK) idxout[(size_t)row * KK + r0] = c0;
    if (r1 < KK) idxout[(size_t)row * KK + r1] = c1;
  }
}

// ---------------- kernel 3: BN statistics over edge norms ----------------
// XCD-swizzled: b = blk&3 so each XCD's L2 caches one batch's gather tables.
__global__ __launch_bounds__(256) void k_stats(
    const float* __restrict__ yF1, const float* __restrict__ yFc,
    const int* __restrict__ idx, double* __restrict__ stats) {
  __shared__ float r1[256], r2[256];
  const int t = threadIdx.x, o = t & 31, nl = t >> 5;
  const int b = blockIdx.x & 3;
  const int n = (blockIdx.x >> 2) * 8 + nl;
  const size_t cb = (size_t)(b * NN + n) * CC + o * 3;
  const float pc0 = yFc[cb], pc1 = yFc[cb + 1], pc2 = yFc[cb + 2];
  const int* ip = idx + (size_t)(b * NN + n) * KK;
  float s1 = 0.f, s2 = 0.f;
  for (int k = 0; k < KK; ++k) {
    int m = ip[k];
    size_t a = (size_t)(b * NN + m) * CC + o * 3;
    float p0 = yF1[a] + pc0, p1 = yF1[a + 1] + pc1, p2 = yF1[a + 2] + pc2;
    float nr = sqrtf(p0 * p0 + p1 * p1 + p2 * p2) + 1e-6f;
    s1 += nr; s2 = fmaf(nr, nr, s2);
  }
  r1[t] = s1; r2[t] = s2; __syncthreads();
  if (t < 128) { r1[t] += r1[t + 128]; r2[t] += r2[t + 128]; } __syncthreads();
  if (t < 64) { r1[t] += r1[t + 64]; r2[t] += r2[t + 64]; } __syncthreads();
  if (t < 32) {
    float a1 = r1[t] + r1[t + 32];
    float a2 = r2[t] + r2[t + 32];
    atomicAdd(&stats[t], (double)a1);
    atomicAdd(&stats[32 + t], (double)a2);
  }
}

// ---------------- kernel 4: BN scale/shift ----------------
__global__ void k_bn(const double* __restrict__ stats, const float* __restrict__ gamma,
                     const float* __restrict__ beta, float* __restrict__ ss) {
  int o = threadIdx.x;
  if (o >= 32) return;
  const double M = (double)BB * NN * KK;
  double mean = stats[o] / M;
  double var = stats[32 + o] / M - mean * mean;
  double inv = 1.0 / sqrt(var + 1e-5);
  ss[o] = (float)((double)gamma[o] * inv);
  ss[32 + o] = (float)((double)beta[o] - mean * (double)gamma[o] * inv);
}

// ---------------- kernel 5: gather + activation + mean over k ----------------
// XCD-swizzled like k_stats.
__global__ __launch_bounds__(256) void k_out(
    const float* __restrict__ yF1, const float* __restrict__ yFc,
    const float* __restrict__ yD1, const float* __restrict__ yDc,
    const int* __restrict__ idx, const float* __restrict__ ss,
    float* __restrict__ out) {
  const int t = threadIdx.x, o = t & 31, nl = t >> 5;
  const int b = blockIdx.x & 3;
  const int n = (blockIdx.x >> 2) * 8 + nl;
  const size_t cb = (size_t)(b * NN + n) * CC + o * 3;
  const float pc0 = yFc[cb], pc1 = yFc[cb + 1], pc2 = yFc[cb + 2];
  const float dc0 = yDc[cb], dc1 = yDc[cb + 1], dc2 = yDc[cb + 2];
  const float sc = ss[o], sh = ss[32 + o];
  const int* ip = idx + (size_t)(b * NN + n) * KK;
  float a0 = 0.f, a1 = 0.f, a2 = 0.f;
  for (int k = 0; k < KK; ++k) {
    int m = ip[k];
    size_t a = (size_t)(b * NN + m) * CC + o * 3;
    float p0 = yF1[a] + pc0, p1 = yF1[a + 1] + pc1, p2 = yF1[a + 2] + pc2;
    float d0 = yD1[a] + dc0, d1 = yD1[a + 1] + dc1, d2 = yD1[a + 2] + dc2;
    float nr = sqrtf(p0 * p0 + p1 * p1 + p2 * p2) + 1e-6f;
    float f = (sc * nr + sh) / nr;
    p0 *= f; p1 *= f; p2 *= f;
    float dt = p0 * d0 + p1 * d1 + p2 * d2;
    float w8 = (dt >= 0.f) ? 0.f : 0.8f * dt / (d0 * d0 + d1 * d1 + d2 * d2 + 1e-6f);
    a0 += p0 - w8 * d0; a1 += p1 - w8 * d1; a2 += p2 - w8 * d2;
  }
  const float inv = 1.f / (float)KK;
  const size_t ob = ((size_t)(b * OO + o) * 3) * NN + n;
  out[ob] = a0 * inv; out[ob + NN] = a1 * inv; out[ob + 2 * NN] = a2 * inv;
}

extern "C" void kernel_launch(void* const* d_in, const int* in_sizes, int n_in,
                              void* d_out, int out_size, void* d_ws, size_t ws_size,
                              hipStream_t stream) {
  (void)in_sizes; (void)n_in; (void)out_size;
  const float* x = (const float*)d_in[0];
  const float* Wf = (const float*)d_in[1];
  const float* Wd = (const float*)d_in[2];
  const float* gamma = (const float*)d_in[3];
  const float* beta = (const float*)d_in[4];
  float* out = (float*)d_out;

  char* ws = (char*)d_ws;
  size_t off = 0;
  auto alloc = [&](size_t bytes) -> void* {
    void* p = ws + off;
    off += (bytes + 255) & ~(size_t)255;
    return p;
  };
  float* yF1 = (float*)alloc((size_t)PTS * CC * 4);
  float* yFc = (float*)alloc((size_t)PTS * CC * 4);
  float* yD1 = (float*)alloc((size_t)PTS * CC * 4);
  float* yDc = (float*)alloc((size_t)PTS * CC * 4);
  float* xneg = (float*)alloc((size_t)PTS * 4);
  int* idx   = (int*)alloc((size_t)PTS * KK * 4);
  double* stats = (double*)alloc(64 * 8);
  float* ss  = (float*)alloc(64 * 4);
  unsigned short* hl = (unsigned short*)alloc((size_t)PTS * 192 * 2);
  float* xT  = (float*)alloc((size_t)PTS * CC * 4);
  unsigned* candbuf = (unsigned*)alloc((size_t)PTS * 48 * 4);
  if (ws_size < off) return;

  hipMemsetAsync(stats, 0, 64 * 8, stream);
  k_feat<<<dim3(PTS / 8), dim3(256), 0, stream>>>(x, Wf, Wd, yF1, yFc, yD1, yDc, xneg);
  k_prep<<<dim3(PTS / 64), dim3(256), 0, stream>>>(x, hl, xT);
  k_dist<<<dim3(BB * NN / 16 * 2), dim3(256), 0, stream>>>(hl, xneg, candbuf);
  k_sel<<<dim3(PTS / 4), dim3(256), 0, stream>>>(candbuf, xT, idx);
  k_stats<<<dim3(PTS / 8), dim3(256), 0, stream>>>(yF1, yFc, idx, stats);
  k_bn<<<dim3(1), dim3(64), 0, stream>>>(stats, gamma, beta, ss);
  k_out<<<dim3(PTS / 8), dim3(256), 0, stream>>>(yF1, yFc, yD1, yDc, idx, ss, out);
}

// Round 11
// 362.062 us; speedup vs baseline: 1.3100x; 1.3100x over previous
//
#include <hip/hip_runtime.h>

// Local context aggregation (DGCNN edge-conv style), MI355X.
// Pipeline:
//   k_feat : per-point transforms -> yG[n]=[F1 96f|D1 96f] (gathered, 3.1MB/batch = L2-fit),
//            yC[n]=[Fc 96f|Dc 96f] (center, streamed), xneg=-0.5|x|^2
//   k_prep : split-bf16 tables hl[n][hi96|lo96] + transposed xT[n][96] f32
//   k_dist : FUSED MFMA score + per-half top-24. 2048 blocks x 256 thr (4 waves),
//            launch_bounds(256,4) — the ONLY no-spill shape (R7/R10: tighter bounds
//            spill; live set ~64 VGPR). v_med3_u32 in-place insert: 12 indep ops/score.
//   k_sel  : per row, f64-score the 48 union candidates (2 lanes/cand), exact top-20.
//   k_stats/k_bn/k_out : BN over edge norms + directional leaky act + mean over k.
//            XCD-swizzled (b=blk&3); gather side reads only yG (L2-resident).
// ws usage: ~42 MB fixed.

namespace {
constexpr int BB = 4;
constexpr int NN = 4096;
constexpr int KK = 20;
constexpr int CC = 96;      // 32 features x 3 dims
constexpr int OO = 32;
constexpr int PTS = BB * NN;
constexpr int LT = 12;      // per-class top list depth (class = 128 cands)
constexpr int TCAND = 24;   // per-half candidates kept
constexpr int NENT = 16 * LT;     // entries per row: 4 waves x 4 kl x 12 = 192
constexpr int NENT_PAD = 196;     // padded row stride (words)
constexpr int RSTRIDE = 100;
}

using bf16x8 = __attribute__((ext_vector_type(8))) short;
using f32x4 = __attribute__((ext_vector_type(4))) float;

__device__ __forceinline__ unsigned short f2bf(float f) {
  unsigned u = __float_as_uint(f);
  return (unsigned short)((u + 0x7fff + ((u >> 16) & 1)) >> 16);
}
__device__ __forceinline__ float bf2f(unsigned short b) {
  return __uint_as_float((unsigned)b << 16);
}
__device__ __forceinline__ unsigned umax32(unsigned a, unsigned b) { return a > b ? a : b; }
__device__ __forceinline__ unsigned med3u(unsigned a, unsigned b, unsigned c) {
  unsigned d;
  asm("v_med3_u32 %0, %1, %2, %3" : "=v"(d) : "v"(a), "v"(b), "v"(c));
  return d;
}

// ---------------- kernel 1: per-point transforms + xneg ----------------
__global__ __launch_bounds__(256) void k_feat(
    const float* __restrict__ x, const float* __restrict__ Wf,
    const float* __restrict__ Wd,
    float* __restrict__ yG, float* __restrict__ yC,
    float* __restrict__ xneg) {
  __shared__ float sW[4][32][32];
  __shared__ float sx[8][RSTRIDE];
  const int t = threadIdx.x;
  for (int i = t; i < 2048; i += 256) {
    int o = i & 31, f = (i >> 5) & 31, which = i >> 10;
    const float* W = which ? Wd : Wf;
    float a1 = W[o * 64 + f], a2 = W[o * 64 + 32 + f];
    sW[which * 2 + 0][f][o] = a1;
    sW[which * 2 + 1][f][o] = a2 - a1;
  }
  const int b = blockIdx.x >> 9;
  const int n0 = (blockIdx.x & 511) * 8;
  for (int i = t; i < 8 * CC; i += 256) {
    int pl = i & 7, c = i >> 3;
    sx[pl][c] = x[((size_t)b * CC + c) * NN + n0 + pl];
  }
  __syncthreads();
  const int o = t & 31, pl = t >> 5;
  float aF1[3] = {0.f, 0.f, 0.f}, aFc[3] = {0.f, 0.f, 0.f};
  float aD1[3] = {0.f, 0.f, 0.f}, aDc[3] = {0.f, 0.f, 0.f};
#pragma unroll
  for (int f = 0; f < 32; ++f) {
    float w0 = sW[0][f][o], w1 = sW[1][f][o];
    float w2 = sW[2][f][o], w3 = sW[3][f][o];
#pragma unroll
    for (int dd = 0; dd < 3; ++dd) {
      float v = sx[pl][f * 3 + dd];
      aF1[dd] = fmaf(w0, v, aF1[dd]);
      aFc[dd] = fmaf(w1, v, aFc[dd]);
      aD1[dd] = fmaf(w2, v, aD1[dd]);
      aDc[dd] = fmaf(w3, v, aDc[dd]);
    }
  }
  const size_t pt = (size_t)(b * NN + n0 + pl) * 192 + o * 3;
#pragma unroll
  for (int dd = 0; dd < 3; ++dd) {
    yG[pt + dd] = aF1[dd]; yG[pt + 96 + dd] = aD1[dd];
    yC[pt + dd] = aFc[dd]; yC[pt + 96 + dd] = aDc[dd];
  }
  float part = 0.f;
#pragma unroll
  for (int dd = 0; dd < 3; ++dd) { float v = sx[pl][o * 3 + dd]; part += v * v; }
#pragma unroll
  for (int off = 16; off >= 1; off >>= 1) part += __shfl_down(part, off, 32);
  if (o == 0) xneg[b * NN + n0 + pl] = -0.5f * part;
}

// ---------------- kernel 1b: split-bf16 + transposed tables ----------------
__global__ __launch_bounds__(256) void k_prep(
    const float* __restrict__ x, unsigned short* __restrict__ hl,
    float* __restrict__ xT) {
  __shared__ float tile[CC][65];
  const int t = threadIdx.x;
  const int b = blockIdx.x >> 6;             // 64 blocks per batch
  const int n0 = (blockIdx.x & 63) * 64;
#pragma unroll
  for (int i = 0; i < 24; ++i) {
    int v = i * 256 + t;
    int c = v >> 6, nn = v & 63;
    tile[c][nn] = x[((size_t)b * CC + c) * NN + n0 + nn];
  }
  __syncthreads();
  // hl rows: [hi 96 | lo 96] bf16, written as 24 x 16B chunks per row
#pragma unroll
  for (int i = 0; i < 6; ++i) {
    int v = i * 256 + t;                    // 0..1535 over 64 rows x 24 chunks
    int row = v / 24, k8 = v % 24;
    unsigned hb[4];
    if (k8 < 12) {
      int c0 = k8 * 8;
#pragma unroll
      for (int j = 0; j < 4; ++j) {
        unsigned short l16 = f2bf(tile[c0 + 2 * j][row]);
        unsigned short h16 = f2bf(tile[c0 + 2 * j + 1][row]);
        hb[j] = (unsigned)l16 | ((unsigned)h16 << 16);
      }
    } else {
      int c0 = (k8 - 12) * 8;
#pragma unroll
      for (int j = 0; j < 4; ++j) {
        float f0 = tile[c0 + 2 * j][row], f1 = tile[c0 + 2 * j + 1][row];
        unsigned short h0 = f2bf(f0), h1 = f2bf(f1);
        unsigned short l0 = f2bf(f0 - bf2f(h0)), l1 = f2bf(f1 - bf2f(h1));
        hb[j] = (unsigned)l0 | ((unsigned)l1 << 16);
      }
    }
    *(uint4*)(hl + (size_t)(b * NN + n0 + row) * 192 + k8 * 8) =
        make_uint4(hb[0], hb[1], hb[2], hb[3]);
  }
  // xT rows: 96 f32 contiguous per point
#pragma unroll
  for (int i = 0; i < 6; ++i) {
    int v = i * 256 + t;
    int row = v / 24, q = v % 24;
    float4 o4;
    o4.x = tile[q * 4 + 0][row]; o4.y = tile[q * 4 + 1][row];
    o4.z = tile[q * 4 + 2][row]; o4.w = tile[q * 4 + 3][row];
    *(float4*)(xT + (size_t)(b * NN + n0 + row) * CC + q * 4) = o4;
  }
}

// ---------------- kernel 2: FUSED MFMA score + per-half top-24 ----------------
// 2048 blocks x 256 thr (4 waves). xcd=wg&7: b=xcd&3, half=xcd>>2. q=wg>>3 -> 16 rows.
// Wave w scans [half*2048 + w*512, +512) over 8 m-tiles of 64.
// key = monotone(score)[31:12] | class[10:7] | (127-local)[6:0]  (unique in block).
__global__ __launch_bounds__(256, 4) void k_dist(
    const unsigned short* __restrict__ hl, const float* __restrict__ xneg,
    unsigned* __restrict__ candbuf) {
  __shared__ unsigned sEnt[16][NENT_PAD];
  const int t = threadIdx.x, lane = t & 63, w = t >> 6;
  const int wg = blockIdx.x;
  const int xcd = wg & 7;
  const int b = xcd & 3;
  const int half = xcd >> 2;
  const int nbase = (wg >> 3) << 4;          // 0..4080, step 16
  const int hoff = half * 2048;
  const int coff = hoff + w * 512;           // this wave's candidate range
  const unsigned short* hb = hl + (size_t)b * NN * 192;
  const int kl = lane >> 4, pr = lane & 15;
  const int cls = w * 4 + kl;                // 0..15
  const unsigned clsbase = (unsigned)(cls << 7);

  // resident operand-B fragments: the block's 16 query rows (col axis)
  bf16x8 rHf[3], rLf[3];
#pragma unroll
  for (int kb = 0; kb < 3; ++kb) {
    const unsigned short* p = hb + (size_t)(nbase + pr) * 192 + (kb * 4 + kl) * 8;
    rHf[kb] = *(const bf16x8*)p;
    rLf[kb] = *(const bf16x8*)(p + 96);
  }

  unsigned ls[LT];
#pragma unroll
  for (int j = 0; j < LT; ++j) ls[j] = 0u;   // 0 == -inf key

  // strength-reduced bases: all inner-loop loads use compile-time immediate offsets
  const unsigned short* pw = hb + ((size_t)coff + pr) * 192 + (size_t)kl * 8;
  const float* px = xneg + (size_t)b * NN + coff + kl * 4;

  for (int mt = 0; mt < 8; ++mt) {
    const unsigned tagbase = clsbase | (unsigned)(127 - mt * 16);
#pragma unroll
    for (int ca = 0; ca < 4; ++ca) {
      const unsigned short* pc = pw + ca * 3072;      // 16 rows * 192 shorts
      f32x4 acc = *(const f32x4*)(px + ca * 16);      // -0.5*|xm|^2 preloaded
      bf16x8 h0 = *(const bf16x8*)(pc);
      bf16x8 l0 = *(const bf16x8*)(pc + 96);
      bf16x8 h1 = *(const bf16x8*)(pc + 32);
      bf16x8 l1 = *(const bf16x8*)(pc + 128);
      bf16x8 h2 = *(const bf16x8*)(pc + 64);
      bf16x8 l2 = *(const bf16x8*)(pc + 160);
      // (candH+candL)·(rowH+rowL) ~= cH·rH + cL·rH + cH·rL  (lo·lo ~2^-16)
      acc = __builtin_amdgcn_mfma_f32_16x16x32_bf16(h0, rHf[0], acc, 0, 0, 0);
      acc = __builtin_amdgcn_mfma_f32_16x16x32_bf16(l0, rHf[0], acc, 0, 0, 0);
      acc = __builtin_amdgcn_mfma_f32_16x16x32_bf16(h0, rLf[0], acc, 0, 0, 0);
      acc = __builtin_amdgcn_mfma_f32_16x16x32_bf16(h1, rHf[1], acc, 0, 0, 0);
      acc = __builtin_amdgcn_mfma_f32_16x16x32_bf16(l1, rHf[1], acc, 0, 0, 0);
      acc = __builtin_amdgcn_mfma_f32_16x16x32_bf16(h1, rLf[1], acc, 0, 0, 0);
      acc = __builtin_amdgcn_mfma_f32_16x16x32_bf16(h2, rHf[2], acc, 0, 0, 0);
      acc = __builtin_amdgcn_mfma_f32_16x16x32_bf16(l2, rHf[2], acc, 0, 0, 0);
      acc = __builtin_amdgcn_mfma_f32_16x16x32_bf16(h2, rLf[2], acc, 0, 0, 0);
      // C/D: col(lane&15)=query row; row((lane>>4)*4+r)=candidate offset.
      const unsigned tag = tagbase - (unsigned)(ca * 4);
#pragma unroll
      for (int r = 0; r < 4; ++r) {
        unsigned sb = __float_as_uint(acc[r]);
        sb ^= ((unsigned)((int)sb >> 31)) | 0x80000000u;
        unsigned key = (sb & 0xFFFFF000u) | (tag - (unsigned)r);
        // in-place parallel sorted-desc insert via med3: every stage reads only
        // pre-insert state (descending j) -> 12 independent ops, depth 1
#pragma unroll
        for (int j = LT - 1; j >= 1; --j)
          ls[j] = med3u(ls[j - 1], ls[j], key);
        ls[0] = umax32(ls[0], key);
      }
    }
    pw += 64 * 192;
    px += 64;
  }
  // dump per-lane sorted key lists: row pr, entries [cls*12 .. +12)
  {
    unsigned* dst = &sEnt[pr][cls * LT];
    *(uint4*)(dst + 0) = make_uint4(ls[0], ls[1], ls[2], ls[3]);
    *(uint4*)(dst + 4) = make_uint4(ls[4], ls[5], ls[6], ls[7]);
    *(uint4*)(dst + 8) = make_uint4(ls[8], ls[9], ls[10], ls[11]);
  }
  __syncthreads();

  // rank-count merge: wave w handles rows w*4..w*4+3; lane owns entries {lane+64c}.
  // Keys unique -> ranks 0..191 a permutation -> all 24 candbuf slots written.
#pragma unroll
  for (int rr = 0; rr < 4; ++rr) {
    const int row = w * 4 + rr;
    unsigned mine[3]; int rk[3] = {0, 0, 0};
#pragma unroll
    for (int c = 0; c < 3; ++c) mine[c] = sEnt[row][lane + 64 * c];
    for (int i4 = 0; i4 < NENT / 4; ++i4) {
      uint4 e = *(const uint4*)&sEnt[row][i4 * 4];
#pragma unroll
      for (int c = 0; c < 3; ++c) {
        rk[c] += (e.x > mine[c]) ? 1 : 0;
        rk[c] += (e.y > mine[c]) ? 1 : 0;
        rk[c] += (e.z > mine[c]) ? 1 : 0;
        rk[c] += (e.w > mine[c]) ? 1 : 0;
      }
    }
#pragma unroll
    for (int c = 0; c < 3; ++c) {
      if (rk[c] < TCAND) {
        unsigned low = mine[c] & 0x7FFu;
        int kcls = (int)(low >> 7);
        int loc = 127 - (int)(low & 127u);
        unsigned id = (unsigned)(hoff + (kcls >> 2) * 512 + (loc >> 4) * 64 +
                                 ((loc >> 2) & 3) * 16 + (kcls & 3) * 4 + (loc & 3));
        candbuf[(size_t)(b * NN + nbase + row) * 48 + half * 24 + rk[c]] = id;
      }
    }
  }
}

// ---------------- kernel 2b: exact f64 top-20 from 48 union candidates ----------------
// One wave per row. 2 lanes per candidate (48 dims each); u64 keys with id tie-break
// (np top_k: ties -> lower index). Ranks unique -> all 20 slots written.
__global__ __launch_bounds__(256) void k_sel(
    const unsigned* __restrict__ candbuf, const float* __restrict__ xT,
    int* __restrict__ idxout) {
  const int t = threadIdx.x, lane = t & 63, w = t >> 6;
  const int row = blockIdx.x * 4 + w;        // 0..16383
  const int b = row >> 12, n = row & (NN - 1);
  const unsigned* cp = candbuf + (size_t)row * 48;
  const int hf = lane & 1;
  unsigned long long k0, k1; int c0, c1;
#pragma unroll
  for (int pass = 0; pass < 2; ++pass) {
    const int ci = pass * 24 + ((lane < 48) ? (lane >> 1) : 23);
    const int mycand = (int)cp[ci];
    const float* xm = xT + ((size_t)b * NN + mycand) * CC + hf * 48;
    const float* xr = xT + ((size_t)b * NN + n) * CC + hf * 48;
    double dot = 0.0, m2 = 0.0;
#pragma unroll 4
    for (int j = 0; j < 12; ++j) {
      float4 a = *(const float4*)&xm[j * 4];
      float4 q = *(const float4*)&xr[j * 4];
      dot = fma((double)q.x, (double)a.x, dot); m2 = fma((double)a.x, (double)a.x, m2);
      dot = fma((double)q.y, (double)a.y, dot); m2 = fma((double)a.y, (double)a.y, m2);
      dot = fma((double)q.z, (double)a.z, dot); m2 = fma((double)a.z, (double)a.z, m2);
      dot = fma((double)q.w, (double)a.w, dot); m2 = fma((double)a.w, (double)a.w, m2);
    }
    dot += __shfl_xor(dot, 1);
    m2 += __shfl_xor(m2, 1);
    double sc = 2.0 * dot - m2;
    unsigned long long bits = (unsigned long long)__double_as_longlong(sc);
    bits ^= ((unsigned long long)((long long)bits >> 63)) | 0x8000000000000000ull;
    unsigned long long key = (bits & ~0xFFFull) | (unsigned long long)(4095 - mycand);
    if (pass == 0) { k0 = key; c0 = mycand; } else { k1 = key; c1 = mycand; }
  }
  int r0 = 0, r1 = 0;
#pragma unroll
  for (int j = 0; j < 24; ++j) {
    unsigned long long a = __shfl(k0, j * 2);
    unsigned long long bb = __shfl(k1, j * 2);
    r0 += (a > k0) ? 1 : 0; r0 += (bb > k0) ? 1 : 0;
    r1 += (a > k1) ? 1 : 0; r1 += (bb > k1) ? 1 : 0;
  }
  if (lane < 48 && hf == 0) {
    if (r0 < KK) idxout[(size_t)row * KK + r0] = c0;
    if (r1 < KK) idxout[(size_t)row * KK + r1] = c1;
  }
}

// ---------------- kernel 3: BN statistics over edge norms ----------------
// XCD-swizzled: b = blk&3. Gathers read the F1 half of yG (L2-resident 3.1MB/batch).
__global__ __launch_bounds__(256) void k_stats(
    const float* __restrict__ yG, const float* __restrict__ yC,
    const int* __restrict__ idx, double* __restrict__ stats) {
  __shared__ float r1[256], r2[256];
  const int t = threadIdx.x, o = t & 31, nl = t >> 5;
  const int b = blockIdx.x & 3;
  const int n = (blockIdx.x >> 2) * 8 + nl;
  const size_t cb = (size_t)(b * NN + n) * 192 + o * 3;
  const float pc0 = yC[cb], pc1 = yC[cb + 1], pc2 = yC[cb + 2];
  const int* ip = idx + (size_t)(b * NN + n) * KK;
  float s1 = 0.f, s2 = 0.f;
  for (int k = 0; k < KK; ++k) {
    int m = ip[k];
    size_t a = (size_t)(b * NN + m) * 192 + o * 3;
    float p0 = yG[a] + pc0, p1 = yG[a + 1] + pc1, p2 = yG[a + 2] + pc2;
    float nr = sqrtf(p0 * p0 + p1 * p1 + p2 * p2) + 1e-6f;
    s1 += nr; s2 = fmaf(nr, nr, s2);
  }
  r1[t] = s1; r2[t] = s2; __syncthreads();
  if (t < 128) { r1[t] += r1[t + 128]; r2[t] += r2[t + 128]; } __syncthreads();
  if (t < 64) { r1[t] += r1[t + 64]; r2[t] += r2[t + 64]; } __syncthreads();
  if (t < 32) {
    float a1 = r1[t] + r1[t + 32];
    float a2 = r2[t] + r2[t + 32];
    atomicAdd(&stats[t], (double)a1);
    atomicAdd(&stats[32 + t], (double)a2);
  }
}

// ---------------- kernel 4: BN scale/shift ----------------
__global__ void k_bn(const double* __restrict__ stats, const float* __restrict__ gamma,
                     const float* __restrict__ beta, float* __restrict__ ss) {
  int o = threadIdx.x;
  if (o >= 32) return;
  const double M = (double)BB * NN * KK;
  double mean = stats[o] / M;
  double var = stats[32 + o] / M - mean * mean;
  double inv = 1.0 / sqrt(var + 1e-5);
  ss[o] = (float)((double)gamma[o] * inv);
  ss[32 + o] = (float)((double)beta[o] - mean * (double)gamma[o] * inv);
}

// ---------------- kernel 5: gather + activation + mean over k ----------------
// XCD-swizzled like k_stats; each gather reads F1+D1 from ONE yG record (same lines).
__global__ __launch_bounds__(256) void k_out(
    const float* __restrict__ yG, const float* __restrict__ yC,
    const int* __restrict__ idx, const float* __restrict__ ss,
    float* __restrict__ out) {
  const int t = threadIdx.x, o = t & 31, nl = t >> 5;
  const int b = blockIdx.x & 3;
  const int n = (blockIdx.x >> 2) * 8 + nl;
  const size_t cb = (size_t)(b * NN + n) * 192 + o * 3;
  const float pc0 = yC[cb], pc1 = yC[cb + 1], pc2 = yC[cb + 2];
  const float dc0 = yC[cb + 96], dc1 = yC[cb + 97], dc2 = yC[cb + 98];
  const float sc = ss[o], sh = ss[32 + o];
  const int* ip = idx + (size_t)(b * NN + n) * KK;
  float a0 = 0.f, a1 = 0.f, a2 = 0.f;
  for (int k = 0; k < KK; ++k) {
    int m = ip[k];
    size_t a = (size_t)(b * NN + m) * 192 + o * 3;
    float p0 = yG[a] + pc0, p1 = yG[a + 1] + pc1, p2 = yG[a + 2] + pc2;
    float d0 = yG[a + 96] + dc0, d1 = yG[a + 97] + dc1, d2 = yG[a + 98] + dc2;
    float nr = sqrtf(p0 * p0 + p1 * p1 + p2 * p2) + 1e-6f;
    float f = (sc * nr + sh) / nr;
    p0 *= f; p1 *= f; p2 *= f;
    float dt = p0 * d0 + p1 * d1 + p2 * d2;
    float w8 = (dt >= 0.f) ? 0.f : 0.8f * dt / (d0 * d0 + d1 * d1 + d2 * d2 + 1e-6f);
    a0 += p0 - w8 * d0; a1 += p1 - w8 * d1; a2 += p2 - w8 * d2;
  }
  const float inv = 1.f / (float)KK;
  const size_t ob = ((size_t)(b * OO + o) * 3) * NN + n;
  out[ob] = a0 * inv; out[ob + NN] = a1 * inv; out[ob + 2 * NN] = a2 * inv;
}

extern "C" void kernel_launch(void* const* d_in, const int* in_sizes, int n_in,
                              void* d_out, int out_size, void* d_ws, size_t ws_size,
                              hipStream_t stream) {
  (void)in_sizes; (void)n_in; (void)out_size;
  const float* x = (const float*)d_in[0];
  const float* Wf = (const float*)d_in[1];
  const float* Wd = (const float*)d_in[2];
  const float* gamma = (const float*)d_in[3];
  const float* beta = (const float*)d_in[4];
  float* out = (float*)d_out;

  char* ws = (char*)d_ws;
  size_t off = 0;
  auto alloc = [&](size_t bytes) -> void* {
    void* p = ws + off;
    off += (bytes + 255) & ~(size_t)255;
    return p;
  };
  float* yG = (float*)alloc((size_t)PTS * 192 * 4);
  float* yC = (float*)alloc((size_t)PTS * 192 * 4);
  float* xneg = (float*)alloc((size_t)PTS * 4);
  int* idx   = (int*)alloc((size_t)PTS * KK * 4);
  double* stats = (double*)alloc(64 * 8);
  float* ss  = (float*)alloc(64 * 4);
  unsigned short* hl = (unsigned short*)alloc((size_t)PTS * 192 * 2);
  float* xT  = (float*)alloc((size_t)PTS * CC * 4);
  unsigned* candbuf = (unsigned*)alloc((size_t)PTS * 48 * 4);
  if (ws_size < off) return;

  hipMemsetAsync(stats, 0, 64 * 8, stream);
  k_feat<<<dim3(PTS / 8), dim3(256), 0, stream>>>(x, Wf, Wd, yG, yC, xneg);
  k_prep<<<dim3(PTS / 64), dim3(256), 0, stream>>>(x, hl, xT);
  k_dist<<<dim3(BB * NN / 16 * 2), dim3(256), 0, stream>>>(hl, xneg, candbuf);
  k_sel<<<dim3(PTS / 4), dim3(256), 0, stream>>>(candbuf, xT, idx);
  k_stats<<<dim3(PTS / 8), dim3(256), 0, stream>>>(yG, yC, idx, stats);
  k_bn<<<dim3(1), dim3(64), 0, stream>>>(stats, gamma, beta, ss);
  k_out<<<dim3(PTS / 8), dim3(256), 0, stream>>>(yG, yC, idx, ss, out);
}

// Round 12
// 356.538 us; speedup vs baseline: 1.3303x; 1.0155x over previous
//
#include <hip/hip_runtime.h>

// Local context aggregation (DGCNN edge-conv style), MI355X.
// Pipeline:
//   k_fp   : FUSED per-point pass: stages x-tile once in LDS ->
//            yG[n]=[F1|D1] (gathered, L2-fit), yC[n]=[Fc|Dc], xneg=-0.5|x|^2,
//            split-bf16 table hl[n][hi96|lo96], transposed xT[n][96].
//   k_dist : FUSED MFMA score + per-half top-24. 2048 blocks x 256 thr (4 waves).
//            launch_bounds(256,3) + mt unroll 2: ILP-deepened pipeline (occupancy is
//            stuck ~3.3 w/SIMD; R8/R10 showed the register-cut path spills/remats, so
//            hide L2 latency inside the wave instead). med3 insert (R11, -10us).
//   k_sel  : per row, f64-score the 48 union candidates (2 lanes/cand), exact top-20.
//   k_stats/k_bn/k_out : BN over edge norms + directional leaky act + mean over k.
//            XCD-swizzled (b=blk&3); gathers read yG (L2-resident 3.1MB/batch).
// ws usage: ~42 MB fixed.

namespace {
constexpr int BB = 4;
constexpr int NN = 4096;
constexpr int KK = 20;
constexpr int CC = 96;      // 32 features x 3 dims
constexpr int OO = 32;
constexpr int PTS = BB * NN;
constexpr int LT = 12;      // per-class top list depth (class = 128 cands)
constexpr int TCAND = 24;   // per-half candidates kept
constexpr int NENT = 16 * LT;     // entries per row: 4 waves x 4 kl x 12 = 192
constexpr int NENT_PAD = 196;     // padded row stride (words)
}

using bf16x8 = __attribute__((ext_vector_type(8))) short;
using f32x4 = __attribute__((ext_vector_type(4))) float;

__device__ __forceinline__ unsigned short f2bf(float f) {
  unsigned u = __float_as_uint(f);
  return (unsigned short)((u + 0x7fff + ((u >> 16) & 1)) >> 16);
}
__device__ __forceinline__ float bf2f(unsigned short b) {
  return __uint_as_float((unsigned)b << 16);
}
__device__ __forceinline__ unsigned umax32(unsigned a, unsigned b) { return a > b ? a : b; }
__device__ __forceinline__ unsigned med3u(unsigned a, unsigned b, unsigned c) {
  unsigned d;
  asm("v_med3_u32 %0, %1, %2, %3" : "=v"(d) : "v"(a), "v"(b), "v"(c));
  return d;
}

// ---------------- kernel 1: fused per-point pass ----------------
// 256 blocks x 256 thr; 64 points/block. One LDS staging of the x-tile feeds
// k_feat's transforms AND k_prep's table builds (R11 ran them as two kernels).
__global__ __launch_bounds__(256) void k_fp(
    const float* __restrict__ x, const float* __restrict__ Wf,
    const float* __restrict__ Wd,
    float* __restrict__ yG, float* __restrict__ yC, float* __restrict__ xneg,
    unsigned short* __restrict__ hl, float* __restrict__ xT) {
  __shared__ float tile[CC][65];   // ~25 KB
  __shared__ float sW[4][32][32];  // 16 KB
  const int t = threadIdx.x;
  const int b = blockIdx.x >> 6;             // 64 blocks per batch
  const int n0 = (blockIdx.x & 63) * 64;
  for (int i = t; i < 2048; i += 256) {
    int o = i & 31, f = (i >> 5) & 31, which = i >> 10;
    const float* W = which ? Wd : Wf;
    float a1 = W[o * 64 + f], a2 = W[o * 64 + 32 + f];
    sW[which * 2 + 0][f][o] = a1;
    sW[which * 2 + 1][f][o] = a2 - a1;
  }
#pragma unroll
  for (int i = 0; i < 24; ++i) {
    int v = i * 256 + t;
    int c = v >> 6, nn = v & 63;
    tile[c][nn] = x[((size_t)b * CC + c) * NN + n0 + nn];
  }
  __syncthreads();

  // ---- k_prep part: hl rows [hi 96 | lo 96] bf16, 24 x 16B chunks per row ----
#pragma unroll
  for (int i = 0; i < 6; ++i) {
    int v = i * 256 + t;                    // 0..1535 over 64 rows x 24 chunks
    int row = v / 24, k8 = v % 24;
    unsigned hb[4];
    if (k8 < 12) {
      int c0 = k8 * 8;
#pragma unroll
      for (int j = 0; j < 4; ++j) {
        unsigned short l16 = f2bf(tile[c0 + 2 * j][row]);
        unsigned short h16 = f2bf(tile[c0 + 2 * j + 1][row]);
        hb[j] = (unsigned)l16 | ((unsigned)h16 << 16);
      }
    } else {
      int c0 = (k8 - 12) * 8;
#pragma unroll
      for (int j = 0; j < 4; ++j) {
        float f0 = tile[c0 + 2 * j][row], f1 = tile[c0 + 2 * j + 1][row];
        unsigned short h0 = f2bf(f0), h1 = f2bf(f1);
        unsigned short l0 = f2bf(f0 - bf2f(h0)), l1 = f2bf(f1 - bf2f(h1));
        hb[j] = (unsigned)l0 | ((unsigned)l1 << 16);
      }
    }
    *(uint4*)(hl + (size_t)(b * NN + n0 + row) * 192 + k8 * 8) =
        make_uint4(hb[0], hb[1], hb[2], hb[3]);
  }
  // xT rows: 96 f32 contiguous per point
#pragma unroll
  for (int i = 0; i < 6; ++i) {
    int v = i * 256 + t;
    int row = v / 24, q = v % 24;
    float4 o4;
    o4.x = tile[q * 4 + 0][row]; o4.y = tile[q * 4 + 1][row];
    o4.z = tile[q * 4 + 2][row]; o4.w = tile[q * 4 + 3][row];
    *(float4*)(xT + (size_t)(b * NN + n0 + row) * CC + q * 4) = o4;
  }

  // ---- k_feat part: thread (o=t&31, pg=t>>5) handles 8 points ----
  const int o = t & 31, pg = t >> 5;
  for (int pp = 0; pp < 8; ++pp) {
    const int pl = pg * 8 + pp;              // point 0..63
    float aF1[3] = {0.f, 0.f, 0.f}, aFc[3] = {0.f, 0.f, 0.f};
    float aD1[3] = {0.f, 0.f, 0.f}, aDc[3] = {0.f, 0.f, 0.f};
#pragma unroll
    for (int f = 0; f < 32; ++f) {
      float w0 = sW[0][f][o], w1 = sW[1][f][o];
      float w2 = sW[2][f][o], w3 = sW[3][f][o];
#pragma unroll
      for (int dd = 0; dd < 3; ++dd) {
        float v = tile[f * 3 + dd][pl];
        aF1[dd] = fmaf(w0, v, aF1[dd]);
        aFc[dd] = fmaf(w1, v, aFc[dd]);
        aD1[dd] = fmaf(w2, v, aD1[dd]);
        aDc[dd] = fmaf(w3, v, aDc[dd]);
      }
    }
    const size_t pt = (size_t)(b * NN + n0 + pl) * 192 + o * 3;
#pragma unroll
    for (int dd = 0; dd < 3; ++dd) {
      yG[pt + dd] = aF1[dd]; yG[pt + 96 + dd] = aD1[dd];
      yC[pt + dd] = aFc[dd]; yC[pt + 96 + dd] = aDc[dd];
    }
  }
  // xneg: one thread per point
  if (t < 64) {
    float s = 0.f;
#pragma unroll 8
    for (int c = 0; c < CC; ++c) { float v = tile[c][t]; s = fmaf(v, v, s); }
    xneg[b * NN + n0 + t] = -0.5f * s;
  }
}

// ---------------- kernel 2: FUSED MFMA score + per-half top-24 ----------------
// 2048 blocks x 256 thr (4 waves). xcd=wg&7: b=xcd&3, half=xcd>>2. q=wg>>3 -> 16 rows.
// Wave w scans [half*2048 + w*512, +512) over 8 m-tiles of 64 (unrolled x2 for ILP).
// key = monotone(score)[31:12] | class[10:7] | (127-local)[6:0]  (unique in block).
__global__ __launch_bounds__(256, 3) void k_dist(
    const unsigned short* __restrict__ hl, const float* __restrict__ xneg,
    unsigned* __restrict__ candbuf) {
  __shared__ unsigned sEnt[16][NENT_PAD];
  const int t = threadIdx.x, lane = t & 63, w = t >> 6;
  const int wg = blockIdx.x;
  const int xcd = wg & 7;
  const int b = xcd & 3;
  const int half = xcd >> 2;
  const int nbase = (wg >> 3) << 4;          // 0..4080, step 16
  const int hoff = half * 2048;
  const int coff = hoff + w * 512;           // this wave's candidate range
  const unsigned short* hb = hl + (size_t)b * NN * 192;
  const int kl = lane >> 4, pr = lane & 15;
  const int cls = w * 4 + kl;                // 0..15
  const unsigned clsbase = (unsigned)(cls << 7);

  // resident operand-B fragments: the block's 16 query rows (col axis)
  bf16x8 rHf[3], rLf[3];
#pragma unroll
  for (int kb = 0; kb < 3; ++kb) {
    const unsigned short* p = hb + (size_t)(nbase + pr) * 192 + (kb * 4 + kl) * 8;
    rHf[kb] = *(const bf16x8*)p;
    rLf[kb] = *(const bf16x8*)(p + 96);
  }

  unsigned ls[LT];
#pragma unroll
  for (int j = 0; j < LT; ++j) ls[j] = 0u;   // 0 == -inf key

  // strength-reduced bases: all inner-loop loads use compile-time immediate offsets
  const unsigned short* pw = hb + ((size_t)coff + pr) * 192 + (size_t)kl * 8;
  const float* px = xneg + (size_t)b * NN + coff + kl * 4;

#pragma unroll 2
  for (int mt = 0; mt < 8; ++mt) {
    const unsigned tagbase = clsbase | (unsigned)(127 - mt * 16);
    const unsigned short* pm = pw + (size_t)mt * (64 * 192);
    const float* pxm = px + mt * 64;
#pragma unroll
    for (int ca = 0; ca < 4; ++ca) {
      const unsigned short* pc = pm + ca * 3072;      // 16 rows * 192 shorts
      f32x4 acc = *(const f32x4*)(pxm + ca * 16);     // -0.5*|xm|^2 preloaded
      bf16x8 h0 = *(const bf16x8*)(pc);
      bf16x8 l0 = *(const bf16x8*)(pc + 96);
      bf16x8 h1 = *(const bf16x8*)(pc + 32);
      bf16x8 l1 = *(const bf16x8*)(pc + 128);
      bf16x8 h2 = *(const bf16x8*)(pc + 64);
      bf16x8 l2 = *(const bf16x8*)(pc + 160);
      // (candH+candL)·(rowH+rowL) ~= cH·rH + cL·rH + cH·rL  (lo·lo ~2^-16)
      acc = __builtin_amdgcn_mfma_f32_16x16x32_bf16(h0, rHf[0], acc, 0, 0, 0);
      acc = __builtin_amdgcn_mfma_f32_16x16x32_bf16(l0, rHf[0], acc, 0, 0, 0);
      acc = __builtin_amdgcn_mfma_f32_16x16x32_bf16(h0, rLf[0], acc, 0, 0, 0);
      acc = __builtin_amdgcn_mfma_f32_16x16x32_bf16(h1, rHf[1], acc, 0, 0, 0);
      acc = __builtin_amdgcn_mfma_f32_16x16x32_bf16(l1, rHf[1], acc, 0, 0, 0);
      acc = __builtin_amdgcn_mfma_f32_16x16x32_bf16(h1, rLf[1], acc, 0, 0, 0);
      acc = __builtin_amdgcn_mfma_f32_16x16x32_bf16(h2, rHf[2], acc, 0, 0, 0);
      acc = __builtin_amdgcn_mfma_f32_16x16x32_bf16(l2, rHf[2], acc, 0, 0, 0);
      acc = __builtin_amdgcn_mfma_f32_16x16x32_bf16(h2, rLf[2], acc, 0, 0, 0);
      // C/D: col(lane&15)=query row; row((lane>>4)*4+r)=candidate offset.
      const unsigned tag = tagbase - (unsigned)(ca * 4);
#pragma unroll
      for (int r = 0; r < 4; ++r) {
        unsigned sb = __float_as_uint(acc[r]);
        sb ^= ((unsigned)((int)sb >> 31)) | 0x80000000u;
        unsigned key = (sb & 0xFFFFF000u) | (tag - (unsigned)r);
        // in-place parallel sorted-desc insert via med3: every stage reads only
        // pre-insert state (descending j) -> 12 independent ops, depth 1
#pragma unroll
        for (int j = LT - 1; j >= 1; --j)
          ls[j] = med3u(ls[j - 1], ls[j], key);
        ls[0] = umax32(ls[0], key);
      }
    }
  }
  // dump per-lane sorted key lists: row pr, entries [cls*12 .. +12)
  {
    unsigned* dst = &sEnt[pr][cls * LT];
    *(uint4*)(dst + 0) = make_uint4(ls[0], ls[1], ls[2], ls[3]);
    *(uint4*)(dst + 4) = make_uint4(ls[4], ls[5], ls[6], ls[7]);
    *(uint4*)(dst + 8) = make_uint4(ls[8], ls[9], ls[10], ls[11]);
  }
  __syncthreads();

  // rank-count merge: wave w handles rows w*4..w*4+3; lane owns entries {lane+64c}.
  // Keys unique -> ranks 0..191 a permutation -> all 24 candbuf slots written.
#pragma unroll
  for (int rr = 0; rr < 4; ++rr) {
    const int row = w * 4 + rr;
    unsigned mine[3]; int rk[3] = {0, 0, 0};
#pragma unroll
    for (int c = 0; c < 3; ++c) mine[c] = sEnt[row][lane + 64 * c];
    for (int i4 = 0; i4 < NENT / 4; ++i4) {
      uint4 e = *(const uint4*)&sEnt[row][i4 * 4];
#pragma unroll
      for (int c = 0; c < 3; ++c) {
        rk[c] += (e.x > mine[c]) ? 1 : 0;
        rk[c] += (e.y > mine[c]) ? 1 : 0;
        rk[c] += (e.z > mine[c]) ? 1 : 0;
        rk[c] += (e.w > mine[c]) ? 1 : 0;
      }
    }
#pragma unroll
    for (int c = 0; c < 3; ++c) {
      if (rk[c] < TCAND) {
        unsigned low = mine[c] & 0x7FFu;
        int kcls = (int)(low >> 7);
        int loc = 127 - (int)(low & 127u);
        unsigned id = (unsigned)(hoff + (kcls >> 2) * 512 + (loc >> 4) * 64 +
                                 ((loc >> 2) & 3) * 16 + (kcls & 3) * 4 + (loc & 3));
        candbuf[(size_t)(b * NN + nbase + row) * 48 + half * 24 + rk[c]] = id;
      }
    }
  }
}

// ---------------- kernel 2b: exact f64 top-20 from 48 union candidates ----------------
// One wave per row. 2 lanes per candidate (48 dims each); u64 keys with id tie-break
// (np top_k: ties -> lower index). Ranks unique -> all 20 slots written.
__global__ __launch_bounds__(256) void k_sel(
    const unsigned* __restrict__ candbuf, const float* __restrict__ xT,
    int* __restrict__ idxout) {
  const int t = threadIdx.x, lane = t & 63, w = t >> 6;
  const int row = blockIdx.x * 4 + w;        // 0..16383
  const int b = row >> 12, n = row & (NN - 1);
  const unsigned* cp = candbuf + (size_t)row * 48;
  const int hf = lane & 1;
  unsigned long long k0, k1; int c0, c1;
#pragma unroll
  for (int pass = 0; pass < 2; ++pass) {
    const int ci = pass * 24 + ((lane < 48) ? (lane >> 1) : 23);
    const int mycand = (int)cp[ci];
    const float* xm = xT + ((size_t)b * NN + mycand) * CC + hf * 48;
    const float* xr = xT + ((size_t)b * NN + n) * CC + hf * 48;
    double dot = 0.0, m2 = 0.0;
#pragma unroll 4
    for (int j = 0; j < 12; ++j) {
      float4 a = *(const float4*)&xm[j * 4];
      float4 q = *(const float4*)&xr[j * 4];
      dot = fma((double)q.x, (double)a.x, dot); m2 = fma((double)a.x, (double)a.x, m2);
      dot = fma((double)q.y, (double)a.y, dot); m2 = fma((double)a.y, (double)a.y, m2);
      dot = fma((double)q.z, (double)a.z, dot); m2 = fma((double)a.z, (double)a.z, m2);
      dot = fma((double)q.w, (double)a.w, dot); m2 = fma((double)a.w, (double)a.w, m2);
    }
    dot += __shfl_xor(dot, 1);
    m2 += __shfl_xor(m2, 1);
    double sc = 2.0 * dot - m2;
    unsigned long long bits = (unsigned long long)__double_as_longlong(sc);
    bits ^= ((unsigned long long)((long long)bits >> 63)) | 0x8000000000000000ull;
    unsigned long long key = (bits & ~0xFFFull) | (unsigned long long)(4095 - mycand);
    if (pass == 0) { k0 = key; c0 = mycand; } else { k1 = key; c1 = mycand; }
  }
  int r0 = 0, r1 = 0;
#pragma unroll
  for (int j = 0; j < 24; ++j) {
    unsigned long long a = __shfl(k0, j * 2);
    unsigned long long bb = __shfl(k1, j * 2);
    r0 += (a > k0) ? 1 : 0; r0 += (bb > k0) ? 1 : 0;
    r1 += (a > k1) ? 1 : 0; r1 += (bb > k1) ? 1 : 0;
  }
  if (lane < 48 && hf == 0) {
    if (r0 < KK) idxout[(size_t)row * KK + r0] = c0;
    if (r1 < KK) idxout[(size_t)row * KK + r1] = c1;
  }
}

// ---------------- kernel 3: BN statistics over edge norms ----------------
// XCD-swizzled: b = blk&3. Gathers read the F1 half of yG (L2-resident 3.1MB/batch).
__global__ __launch_bounds__(256) void k_stats(
    const float* __restrict__ yG, const float* __restrict__ yC,
    const int* __restrict__ idx, double* __restrict__ stats) {
  __shared__ float r1[256], r2[256];
  const int t = threadIdx.x, o = t & 31, nl = t >> 5;
  const int b = blockIdx.x & 3;
  const int n = (blockIdx.x >> 2) * 8 + nl;
  const size_t cb = (size_t)(b * NN + n) * 192 + o * 3;
  const float pc0 = yC[cb], pc1 = yC[cb + 1], pc2 = yC[cb + 2];
  const int* ip = idx + (size_t)(b * NN + n) * KK;
  float s1 = 0.f, s2 = 0.f;
  for (int k = 0; k < KK; ++k) {
    int m = ip[k];
    size_t a = (size_t)(b * NN + m) * 192 + o * 3;
    float p0 = yG[a] + pc0, p1 = yG[a + 1] + pc1, p2 = yG[a + 2] + pc2;
    float nr = sqrtf(p0 * p0 + p1 * p1 + p2 * p2) + 1e-6f;
    s1 += nr; s2 = fmaf(nr, nr, s2);
  }
  r1[t] = s1; r2[t] = s2; __syncthreads();
  if (t < 128) { r1[t] += r1[t + 128]; r2[t] += r2[t + 128]; } __syncthreads();
  if (t < 64) { r1[t] += r1[t + 64]; r2[t] += r2[t + 64]; } __syncthreads();
  if (t < 32) {
    float a1 = r1[t] + r1[t + 32];
    float a2 = r2[t] + r2[t + 32];
    atomicAdd(&stats[t], (double)a1);
    atomicAdd(&stats[32 + t], (double)a2);
  }
}

// ---------------- kernel 4: BN scale/shift ----------------
__global__ void k_bn(const double* __restrict__ stats, const float* __restrict__ gamma,
                     const float* __restrict__ beta, float* __restrict__ ss) {
  int o = threadIdx.x;
  if (o >= 32) return;
  const double M = (double)BB * NN * KK;
  double mean = stats[o] / M;
  double var = stats[32 + o] / M - mean * mean;
  double inv = 1.0 / sqrt(var + 1e-5);
  ss[o] = (float)((double)gamma[o] * inv);
  ss[32 + o] = (float)((double)beta[o] - mean * (double)gamma[o] * inv);
}

// ---------------- kernel 5: gather + activation + mean over k ----------------
// XCD-swizzled like k_stats; each gather reads F1+D1 from ONE yG record (same lines).
__global__ __launch_bounds__(256) void k_out(
    const float* __restrict__ yG, const float* __restrict__ yC,
    const int* __restrict__ idx, const float* __restrict__ ss,
    float* __restrict__ out) {
  const int t = threadIdx.x, o = t & 31, nl = t >> 5;
  const int b = blockIdx.x & 3;
  const int n = (blockIdx.x >> 2) * 8 + nl;
  const size_t cb = (size_t)(b * NN + n) * 192 + o * 3;
  const float pc0 = yC[cb], pc1 = yC[cb + 1], pc2 = yC[cb + 2];
  const float dc0 = yC[cb + 96], dc1 = yC[cb + 97], dc2 = yC[cb + 98];
  const float sc = ss[o], sh = ss[32 + o];
  const int* ip = idx + (size_t)(b * NN + n) * KK;
  float a0 = 0.f, a1 = 0.f, a2 = 0.f;
  for (int k = 0; k < KK; ++k) {
    int m = ip[k];
    size_t a = (size_t)(b * NN + m) * 192 + o * 3;
    float p0 = yG[a] + pc0, p1 = yG[a + 1] + pc1, p2 = yG[a + 2] + pc2;
    float d0 = yG[a + 96] + dc0, d1 = yG[a + 97] + dc1, d2 = yG[a + 98] + dc2;
    float nr = sqrtf(p0 * p0 + p1 * p1 + p2 * p2) + 1e-6f;
    float f = (sc * nr + sh) / nr;
    p0 *= f; p1 *= f; p2 *= f;
    float dt = p0 * d0 + p1 * d1 + p2 * d2;
    float w8 = (dt >= 0.f) ? 0.f : 0.8f * dt / (d0 * d0 + d1 * d1 + d2 * d2 + 1e-6f);
    a0 += p0 - w8 * d0; a1 += p1 - w8 * d1; a2 += p2 - w8 * d2;
  }
  const float inv = 1.f / (float)KK;
  const size_t ob = ((size_t)(b * OO + o) * 3) * NN + n;
  out[ob] = a0 * inv; out[ob + NN] = a1 * inv; out[ob + 2 * NN] = a2 * inv;
}

extern "C" void kernel_launch(void* const* d_in, const int* in_sizes, int n_in,
                              void* d_out, int out_size, void* d_ws, size_t ws_size,
                              hipStream_t stream) {
  (void)in_sizes; (void)n_in; (void)out_size;
  const float* x = (const float*)d_in[0];
  const float* Wf = (const float*)d_in[1];
  const float* Wd = (const float*)d_in[2];
  const float* gamma = (const float*)d_in[3];
  const float* beta = (const float*)d_in[4];
  float* out = (float*)d_out;

  char* ws = (char*)d_ws;
  size_t off = 0;
  auto alloc = [&](size_t bytes) -> void* {
    void* p = ws + off;
    off += (bytes + 255) & ~(size_t)255;
    return p;
  };
  float* yG = (float*)alloc((size_t)PTS * 192 * 4);
  float* yC = (float*)alloc((size_t)PTS * 192 * 4);
  float* xneg = (float*)alloc((size_t)PTS * 4);
  int* idx   = (int*)alloc((size_t)PTS * KK * 4);
  double* stats = (double*)alloc(64 * 8);
  float* ss  = (float*)alloc(64 * 4);
  unsigned short* hl = (unsigned short*)alloc((size_t)PTS * 192 * 2);
  float* xT  = (float*)alloc((size_t)PTS * CC * 4);
  unsigned* candbuf = (unsigned*)alloc((size_t)PTS * 48 * 4);
  if (ws_size < off) return;

  hipMemsetAsync(stats, 0, 64 * 8, stream);
  k_fp<<<dim3(PTS / 64), dim3(256), 0, stream>>>(x, Wf, Wd, yG, yC, xneg, hl, xT);
  k_dist<<<dim3(BB * NN / 16 * 2), dim3(256), 0, stream>>>(hl, xneg, candbuf);
  k_sel<<<dim3(PTS / 4), dim3(256), 0, stream>>>(candbuf, xT, idx);
  k_stats<<<dim3(PTS / 8), dim3(256), 0, stream>>>(yG, yC, idx, stats);
  k_bn<<<dim3(1), dim3(64), 0, stream>>>(stats, gamma, beta, ss);
  k_out<<<dim3(PTS / 8), dim3(256), 0, stream>>>(yG, yC, idx, ss, out);
}

// Round 13
// 326.049 us; speedup vs baseline: 1.4547x; 1.0935x over previous
//
#include <hip/hip_runtime.h>

// Local context aggregation (DGCNN edge-conv style), MI355X.
// Pipeline (4 launches):
//   k_fp      : FUSED per-point pass: yG[n]=[F1|D1] (gather table, L2-fit/batch),
//               yC[n]=[Fc|Dc], xneg=-0.5|x|^2, split-bf16 hl[n][hi96|lo96], xT[n][96].
//   k_dist    : FUSED MFMA score + per-half top-24 (byte-identical to R12: 2048x256,
//               (256,3), med3 insert, rank-count merge -> candbuf).
//   k_selstats: FUSED f64 re-rank (top-20 -> idx) + BN norm statistics. 512 thr,
//               8 rows/block, LDS block-reduce -> 64 atomics/block (same as old k_stats).
//   k_out     : BN scale/shift computed in-block from stats (k_bn inlined) + gather +
//               directional leaky act + mean over k. XCD-swizzled (b=blk&3).
// ws usage: ~42 MB fixed.

namespace {
constexpr int BB = 4;
constexpr int NN = 4096;
constexpr int KK = 20;
constexpr int CC = 96;      // 32 features x 3 dims
constexpr int OO = 32;
constexpr int PTS = BB * NN;
constexpr int LT = 12;      // per-class top list depth (class = 128 cands)
constexpr int TCAND = 24;   // per-half candidates kept
constexpr int NENT = 16 * LT;     // entries per row: 4 waves x 4 kl x 12 = 192
constexpr int NENT_PAD = 196;     // padded row stride (words)
}

using bf16x8 = __attribute__((ext_vector_type(8))) short;
using f32x4 = __attribute__((ext_vector_type(4))) float;

__device__ __forceinline__ unsigned short f2bf(float f) {
  unsigned u = __float_as_uint(f);
  return (unsigned short)((u + 0x7fff + ((u >> 16) & 1)) >> 16);
}
__device__ __forceinline__ float bf2f(unsigned short b) {
  return __uint_as_float((unsigned)b << 16);
}
__device__ __forceinline__ unsigned umax32(unsigned a, unsigned b) { return a > b ? a : b; }
__device__ __forceinline__ unsigned med3u(unsigned a, unsigned b, unsigned c) {
  unsigned d;
  asm("v_med3_u32 %0, %1, %2, %3" : "=v"(d) : "v"(a), "v"(b), "v"(c));
  return d;
}

// ---------------- kernel 1: fused per-point pass ----------------
__global__ __launch_bounds__(256) void k_fp(
    const float* __restrict__ x, const float* __restrict__ Wf,
    const float* __restrict__ Wd,
    float* __restrict__ yG, float* __restrict__ yC, float* __restrict__ xneg,
    unsigned short* __restrict__ hl, float* __restrict__ xT) {
  __shared__ float tile[CC][65];   // ~25 KB
  __shared__ float sW[4][32][32];  // 16 KB
  const int t = threadIdx.x;
  const int b = blockIdx.x >> 6;             // 64 blocks per batch
  const int n0 = (blockIdx.x & 63) * 64;
  for (int i = t; i < 2048; i += 256) {
    int o = i & 31, f = (i >> 5) & 31, which = i >> 10;
    const float* W = which ? Wd : Wf;
    float a1 = W[o * 64 + f], a2 = W[o * 64 + 32 + f];
    sW[which * 2 + 0][f][o] = a1;
    sW[which * 2 + 1][f][o] = a2 - a1;
  }
#pragma unroll
  for (int i = 0; i < 24; ++i) {
    int v = i * 256 + t;
    int c = v >> 6, nn = v & 63;
    tile[c][nn] = x[((size_t)b * CC + c) * NN + n0 + nn];
  }
  __syncthreads();

  // ---- split-bf16 table: hl rows [hi 96 | lo 96], 24 x 16B chunks per row ----
#pragma unroll
  for (int i = 0; i < 6; ++i) {
    int v = i * 256 + t;                    // 0..1535 over 64 rows x 24 chunks
    int row = v / 24, k8 = v % 24;
    unsigned hb[4];
    if (k8 < 12) {
      int c0 = k8 * 8;
#pragma unroll
      for (int j = 0; j < 4; ++j) {
        unsigned short l16 = f2bf(tile[c0 + 2 * j][row]);
        unsigned short h16 = f2bf(tile[c0 + 2 * j + 1][row]);
        hb[j] = (unsigned)l16 | ((unsigned)h16 << 16);
      }
    } else {
      int c0 = (k8 - 12) * 8;
#pragma unroll
      for (int j = 0; j < 4; ++j) {
        float f0 = tile[c0 + 2 * j][row], f1 = tile[c0 + 2 * j + 1][row];
        unsigned short h0 = f2bf(f0), h1 = f2bf(f1);
        unsigned short l0 = f2bf(f0 - bf2f(h0)), l1 = f2bf(f1 - bf2f(h1));
        hb[j] = (unsigned)l0 | ((unsigned)l1 << 16);
      }
    }
    *(uint4*)(hl + (size_t)(b * NN + n0 + row) * 192 + k8 * 8) =
        make_uint4(hb[0], hb[1], hb[2], hb[3]);
  }
  // xT rows: 96 f32 contiguous per point
#pragma unroll
  for (int i = 0; i < 6; ++i) {
    int v = i * 256 + t;
    int row = v / 24, q = v % 24;
    float4 o4;
    o4.x = tile[q * 4 + 0][row]; o4.y = tile[q * 4 + 1][row];
    o4.z = tile[q * 4 + 2][row]; o4.w = tile[q * 4 + 3][row];
    *(float4*)(xT + (size_t)(b * NN + n0 + row) * CC + q * 4) = o4;
  }

  // ---- transforms: thread (o=t&31, pg=t>>5) handles 8 points ----
  const int o = t & 31, pg = t >> 5;
  for (int pp = 0; pp < 8; ++pp) {
    const int pl = pg * 8 + pp;              // point 0..63
    float aF1[3] = {0.f, 0.f, 0.f}, aFc[3] = {0.f, 0.f, 0.f};
    float aD1[3] = {0.f, 0.f, 0.f}, aDc[3] = {0.f, 0.f, 0.f};
#pragma unroll
    for (int f = 0; f < 32; ++f) {
      float w0 = sW[0][f][o], w1 = sW[1][f][o];
      float w2 = sW[2][f][o], w3 = sW[3][f][o];
#pragma unroll
      for (int dd = 0; dd < 3; ++dd) {
        float v = tile[f * 3 + dd][pl];
        aF1[dd] = fmaf(w0, v, aF1[dd]);
        aFc[dd] = fmaf(w1, v, aFc[dd]);
        aD1[dd] = fmaf(w2, v, aD1[dd]);
        aDc[dd] = fmaf(w3, v, aDc[dd]);
      }
    }
    const size_t pt = (size_t)(b * NN + n0 + pl) * 192 + o * 3;
#pragma unroll
    for (int dd = 0; dd < 3; ++dd) {
      yG[pt + dd] = aF1[dd]; yG[pt + 96 + dd] = aD1[dd];
      yC[pt + dd] = aFc[dd]; yC[pt + 96 + dd] = aDc[dd];
    }
  }
  // xneg: one thread per point
  if (t < 64) {
    float s = 0.f;
#pragma unroll 8
    for (int c = 0; c < CC; ++c) { float v = tile[c][t]; s = fmaf(v, v, s); }
    xneg[b * NN + n0 + t] = -0.5f * s;
  }
}

// ---------------- kernel 2: FUSED MFMA score + per-half top-24 ----------------
// 2048 blocks x 256 thr (4 waves). xcd=wg&7: b=xcd&3, half=xcd>>2. q=wg>>3 -> 16 rows.
// Wave w scans [half*2048 + w*512, +512) over 8 m-tiles of 64 (unrolled x2).
// key = monotone(score)[31:12] | class[10:7] | (127-local)[6:0]  (unique in block).
__global__ __launch_bounds__(256, 3) void k_dist(
    const unsigned short* __restrict__ hl, const float* __restrict__ xneg,
    unsigned* __restrict__ candbuf) {
  __shared__ unsigned sEnt[16][NENT_PAD];
  const int t = threadIdx.x, lane = t & 63, w = t >> 6;
  const int wg = blockIdx.x;
  const int xcd = wg & 7;
  const int b = xcd & 3;
  const int half = xcd >> 2;
  const int nbase = (wg >> 3) << 4;          // 0..4080, step 16
  const int hoff = half * 2048;
  const int coff = hoff + w * 512;           // this wave's candidate range
  const unsigned short* hb = hl + (size_t)b * NN * 192;
  const int kl = lane >> 4, pr = lane & 15;
  const int cls = w * 4 + kl;                // 0..15
  const unsigned clsbase = (unsigned)(cls << 7);

  // resident operand-B fragments: the block's 16 query rows (col axis)
  bf16x8 rHf[3], rLf[3];
#pragma unroll
  for (int kb = 0; kb < 3; ++kb) {
    const unsigned short* p = hb + (size_t)(nbase + pr) * 192 + (kb * 4 + kl) * 8;
    rHf[kb] = *(const bf16x8*)p;
    rLf[kb] = *(const bf16x8*)(p + 96);
  }

  unsigned ls[LT];
#pragma unroll
  for (int j = 0; j < LT; ++j) ls[j] = 0u;   // 0 == -inf key

  // strength-reduced bases: all inner-loop loads use compile-time immediate offsets
  const unsigned short* pw = hb + ((size_t)coff + pr) * 192 + (size_t)kl * 8;
  const float* px = xneg + (size_t)b * NN + coff + kl * 4;

#pragma unroll 2
  for (int mt = 0; mt < 8; ++mt) {
    const unsigned tagbase = clsbase | (unsigned)(127 - mt * 16);
    const unsigned short* pm = pw + (size_t)mt * (64 * 192);
    const float* pxm = px + mt * 64;
#pragma unroll
    for (int ca = 0; ca < 4; ++ca) {
      const unsigned short* pc = pm + ca * 3072;      // 16 rows * 192 shorts
      f32x4 acc = *(const f32x4*)(pxm + ca * 16);     // -0.5*|xm|^2 preloaded
      bf16x8 h0 = *(const bf16x8*)(pc);
      bf16x8 l0 = *(const bf16x8*)(pc + 96);
      bf16x8 h1 = *(const bf16x8*)(pc + 32);
      bf16x8 l1 = *(const bf16x8*)(pc + 128);
      bf16x8 h2 = *(const bf16x8*)(pc + 64);
      bf16x8 l2 = *(const bf16x8*)(pc + 160);
      // (candH+candL)·(rowH+rowL) ~= cH·rH + cL·rH + cH·rL  (lo·lo ~2^-16)
      acc = __builtin_amdgcn_mfma_f32_16x16x32_bf16(h0, rHf[0], acc, 0, 0, 0);
      acc = __builtin_amdgcn_mfma_f32_16x16x32_bf16(l0, rHf[0], acc, 0, 0, 0);
      acc = __builtin_amdgcn_mfma_f32_16x16x32_bf16(h0, rLf[0], acc, 0, 0, 0);
      acc = __builtin_amdgcn_mfma_f32_16x16x32_bf16(h1, rHf[1], acc, 0, 0, 0);
      acc = __builtin_amdgcn_mfma_f32_16x16x32_bf16(l1, rHf[1], acc, 0, 0, 0);
      acc = __builtin_amdgcn_mfma_f32_16x16x32_bf16(h1, rLf[1], acc, 0, 0, 0);
      acc = __builtin_amdgcn_mfma_f32_16x16x32_bf16(h2, rHf[2], acc, 0, 0, 0);
      acc = __builtin_amdgcn_mfma_f32_16x16x32_bf16(l2, rHf[2], acc, 0, 0, 0);
      acc = __builtin_amdgcn_mfma_f32_16x16x32_bf16(h2, rLf[2], acc, 0, 0, 0);
      // C/D: col(lane&15)=query row; row((lane>>4)*4+r)=candidate offset.
      const unsigned tag = tagbase - (unsigned)(ca * 4);
#pragma unroll
      for (int r = 0; r < 4; ++r) {
        unsigned sb = __float_as_uint(acc[r]);
        sb ^= ((unsigned)((int)sb >> 31)) | 0x80000000u;
        unsigned key = (sb & 0xFFFFF000u) | (tag - (unsigned)r);
        // in-place parallel sorted-desc insert via med3 (reads pre-insert state)
#pragma unroll
        for (int j = LT - 1; j >= 1; --j)
          ls[j] = med3u(ls[j - 1], ls[j], key);
        ls[0] = umax32(ls[0], key);
      }
    }
  }
  // dump per-lane sorted key lists: row pr, entries [cls*12 .. +12)
  {
    unsigned* dst = &sEnt[pr][cls * LT];
    *(uint4*)(dst + 0) = make_uint4(ls[0], ls[1], ls[2], ls[3]);
    *(uint4*)(dst + 4) = make_uint4(ls[4], ls[5], ls[6], ls[7]);
    *(uint4*)(dst + 8) = make_uint4(ls[8], ls[9], ls[10], ls[11]);
  }
  __syncthreads();

  // rank-count merge: wave w handles rows w*4..w*4+3; lane owns entries {lane+64c}.
  // Keys unique -> ranks 0..191 a permutation -> all 24 candbuf slots written.
#pragma unroll
  for (int rr = 0; rr < 4; ++rr) {
    const int row = w * 4 + rr;
    unsigned mine[3]; int rk[3] = {0, 0, 0};
#pragma unroll
    for (int c = 0; c < 3; ++c) mine[c] = sEnt[row][lane + 64 * c];
    for (int i4 = 0; i4 < NENT / 4; ++i4) {
      uint4 e = *(const uint4*)&sEnt[row][i4 * 4];
#pragma unroll
      for (int c = 0; c < 3; ++c) {
        rk[c] += (e.x > mine[c]) ? 1 : 0;
        rk[c] += (e.y > mine[c]) ? 1 : 0;
        rk[c] += (e.z > mine[c]) ? 1 : 0;
        rk[c] += (e.w > mine[c]) ? 1 : 0;
      }
    }
#pragma unroll
    for (int c = 0; c < 3; ++c) {
      if (rk[c] < TCAND) {
        unsigned low = mine[c] & 0x7FFu;
        int kcls = (int)(low >> 7);
        int loc = 127 - (int)(low & 127u);
        unsigned id = (unsigned)(hoff + (kcls >> 2) * 512 + (loc >> 4) * 64 +
                                 ((loc >> 2) & 3) * 16 + (kcls & 3) * 4 + (loc & 3));
        candbuf[(size_t)(b * NN + nbase + row) * 48 + half * 24 + rk[c]] = id;
      }
    }
  }
}

// ---------------- kernel 3: FUSED exact f64 top-20 + BN statistics ----------------
// 512 thr = 8 waves, 8 rows/block, grid PTS/8, XCD-swizzled (b=blk&3).
// Phase A (per wave): f64-score 48 union candidates (2 lanes/cand, 48 dims each),
//   u64 keys with id tie-break (np top_k ties -> lower index) -> idx + LDS sTop.
// Phase B (per wave): norm sums over the row's 20 neighbors, lane=(channel, k-parity);
//   LDS block-reduce -> 64 atomics/block (same contention as the old k_stats).
__global__ __launch_bounds__(512) void k_selstats(
    const unsigned* __restrict__ candbuf, const float* __restrict__ xT,
    const float* __restrict__ yG, const float* __restrict__ yC,
    int* __restrict__ idxout, double* __restrict__ stats) {
  __shared__ int sTop[8][KK];
  __shared__ float rs1[8][32], rs2[8][32];
  const int t = threadIdx.x, lane = t & 63, w = t >> 6;
  const int b = blockIdx.x & 3;
  const int n = (blockIdx.x >> 2) * 8 + w;
  const int row = b * NN + n;
  const unsigned* cp = candbuf + (size_t)row * 48;
  const int hf = lane & 1;
  unsigned long long k0, k1; int c0, c1;
#pragma unroll
  for (int pass = 0; pass < 2; ++pass) {
    const int ci = pass * 24 + ((lane < 48) ? (lane >> 1) : 23);
    const int mycand = (int)cp[ci];
    const float* xm = xT + ((size_t)b * NN + mycand) * CC + hf * 48;
    const float* xr = xT + ((size_t)b * NN + n) * CC + hf * 48;
    double dot = 0.0, m2 = 0.0;
#pragma unroll 4
    for (int j = 0; j < 12; ++j) {
      float4 a = *(const float4*)&xm[j * 4];
      float4 q = *(const float4*)&xr[j * 4];
      dot = fma((double)q.x, (double)a.x, dot); m2 = fma((double)a.x, (double)a.x, m2);
      dot = fma((double)q.y, (double)a.y, dot); m2 = fma((double)a.y, (double)a.y, m2);
      dot = fma((double)q.z, (double)a.z, dot); m2 = fma((double)a.z, (double)a.z, m2);
      dot = fma((double)q.w, (double)a.w, dot); m2 = fma((double)a.w, (double)a.w, m2);
    }
    dot += __shfl_xor(dot, 1);
    m2 += __shfl_xor(m2, 1);
    double sc = 2.0 * dot - m2;
    unsigned long long bits = (unsigned long long)__double_as_longlong(sc);
    bits ^= ((unsigned long long)((long long)bits >> 63)) | 0x8000000000000000ull;
    unsigned long long key = (bits & ~0xFFFull) | (unsigned long long)(4095 - mycand);
    if (pass == 0) { k0 = key; c0 = mycand; } else { k1 = key; c1 = mycand; }
  }
  int r0c = 0, r1c = 0;
#pragma unroll
  for (int j = 0; j < 24; ++j) {
    unsigned long long a = __shfl(k0, j * 2);
    unsigned long long bb = __shfl(k1, j * 2);
    r0c += (a > k0) ? 1 : 0; r0c += (bb > k0) ? 1 : 0;
    r1c += (a > k1) ? 1 : 0; r1c += (bb > k1) ? 1 : 0;
  }
  if (lane < 48 && hf == 0) {
    if (r0c < KK) { idxout[(size_t)row * KK + r0c] = c0; sTop[w][r0c] = c0; }
    if (r1c < KK) { idxout[(size_t)row * KK + r1c] = c1; sTop[w][r1c] = c1; }
  }
  __builtin_amdgcn_wave_barrier();  // same-wave LDS write->read fence (compile-time)

  // ---- phase B: norm statistics for this row ----
  const int o = lane & 31, kh = lane >> 5;
  const size_t cb = (size_t)row * 192 + o * 3;
  const float pc0 = yC[cb], pc1 = yC[cb + 1], pc2 = yC[cb + 2];
  float s1 = 0.f, s2 = 0.f;
#pragma unroll
  for (int j = 0; j < 10; ++j) {
    int m = sTop[w][2 * j + kh];
    size_t a = ((size_t)b * NN + m) * 192 + o * 3;
    float p0 = yG[a] + pc0, p1 = yG[a + 1] + pc1, p2 = yG[a + 2] + pc2;
    float nr = sqrtf(p0 * p0 + p1 * p1 + p2 * p2) + 1e-6f;
    s1 += nr; s2 = fmaf(nr, nr, s2);
  }
  s1 += __shfl_xor(s1, 32);
  s2 += __shfl_xor(s2, 32);
  if (lane < 32) { rs1[w][o] = s1; rs2[w][o] = s2; }
  __syncthreads();
  if (t < 32) {
    float a1 = 0.f, a2 = 0.f;
#pragma unroll
    for (int ww = 0; ww < 8; ++ww) { a1 += rs1[ww][t]; a2 += rs2[ww][t]; }
    atomicAdd(&stats[t], (double)a1);
    atomicAdd(&stats[32 + t], (double)a2);
  }
}

// ---------------- kernel 4: gather + activation + mean over k (BN inlined) ----------------
// XCD-swizzled (b=blk&3); per-block BN scale/shift from stats (k_bn inlined, ~20 f64 ops).
__global__ __launch_bounds__(256) void k_out(
    const float* __restrict__ yG, const float* __restrict__ yC,
    const int* __restrict__ idx, const double* __restrict__ stats,
    const float* __restrict__ gamma, const float* __restrict__ beta,
    float* __restrict__ out) {
  __shared__ float sS[64];
  const int t = threadIdx.x, o = t & 31, nl = t >> 5;
  if (t < 32) {
    const double M = (double)BB * NN * KK;
    double mean = stats[t] / M;
    double var = stats[32 + t] / M - mean * mean;
    double inv = 1.0 / sqrt(var + 1e-5);
    sS[t] = (float)((double)gamma[t] * inv);
    sS[32 + t] = (float)((double)beta[t] - mean * (double)gamma[t] * inv);
  }
  __syncthreads();
  const int b = blockIdx.x & 3;
  const int n = (blockIdx.x >> 2) * 8 + nl;
  const size_t cb = (size_t)(b * NN + n) * 192 + o * 3;
  const float pc0 = yC[cb], pc1 = yC[cb + 1], pc2 = yC[cb + 2];
  const float dc0 = yC[cb + 96], dc1 = yC[cb + 97], dc2 = yC[cb + 98];
  const float sc = sS[o], sh = sS[32 + o];
  const int* ip = idx + (size_t)(b * NN + n) * KK;
  float a0 = 0.f, a1 = 0.f, a2 = 0.f;
  for (int k = 0; k < KK; ++k) {
    int m = ip[k];
    size_t a = (size_t)(b * NN + m) * 192 + o * 3;
    float p0 = yG[a] + pc0, p1 = yG[a + 1] + pc1, p2 = yG[a + 2] + pc2;
    float d0 = yG[a + 96] + dc0, d1 = yG[a + 97] + dc1, d2 = yG[a + 98] + dc2;
    float nr = sqrtf(p0 * p0 + p1 * p1 + p2 * p2) + 1e-6f;
    float f = (sc * nr + sh) / nr;
    p0 *= f; p1 *= f; p2 *= f;
    float dt = p0 * d0 + p1 * d1 + p2 * d2;
    float w8 = (dt >= 0.f) ? 0.f : 0.8f * dt / (d0 * d0 + d1 * d1 + d2 * d2 + 1e-6f);
    a0 += p0 - w8 * d0; a1 += p1 - w8 * d1; a2 += p2 - w8 * d2;
  }
  const float inv = 1.f / (float)KK;
  const size_t ob = ((size_t)(b * OO + o) * 3) * NN + n;
  out[ob] = a0 * inv; out[ob + NN] = a1 * inv; out[ob + 2 * NN] = a2 * inv;
}

extern "C" void kernel_launch(void* const* d_in, const int* in_sizes, int n_in,
                              void* d_out, int out_size, void* d_ws, size_t ws_size,
                              hipStream_t stream) {
  (void)in_sizes; (void)n_in; (void)out_size;
  const float* x = (const float*)d_in[0];
  const float* Wf = (const float*)d_in[1];
  const float* Wd = (const float*)d_in[2];
  const float* gamma = (const float*)d_in[3];
  const float* beta = (const float*)d_in[4];
  float* out = (float*)d_out;

  char* ws = (char*)d_ws;
  size_t off = 0;
  auto alloc = [&](size_t bytes) -> void* {
    void* p = ws + off;
    off += (bytes + 255) & ~(size_t)255;
    return p;
  };
  float* yG = (float*)alloc((size_t)PTS * 192 * 4);
  float* yC = (float*)alloc((size_t)PTS * 192 * 4);
  float* xneg = (float*)alloc((size_t)PTS * 4);
  int* idx   = (int*)alloc((size_t)PTS * KK * 4);
  double* stats = (double*)alloc(64 * 8);
  unsigned short* hl = (unsigned short*)alloc((size_t)PTS * 192 * 2);
  float* xT  = (float*)alloc((size_t)PTS * CC * 4);
  unsigned* candbuf = (unsigned*)alloc((size_t)PTS * 48 * 4);
  if (ws_size < off) return;

  hipMemsetAsync(stats, 0, 64 * 8, stream);
  k_fp<<<dim3(PTS / 64), dim3(256), 0, stream>>>(x, Wf, Wd, yG, yC, xneg, hl, xT);
  k_dist<<<dim3(BB * NN / 16 * 2), dim3(256), 0, stream>>>(hl, xneg, candbuf);
  k_selstats<<<dim3(PTS / 8), dim3(512), 0, stream>>>(candbuf, xT, yG, yC, idx, stats);
  k_out<<<dim3(PTS / 8), dim3(256), 0, stream>>>(yG, yC, idx, stats, gamma, beta, out);
}

// Round 14
// 324.994 us; speedup vs baseline: 1.4594x; 1.0032x over previous
//
#include <hip/hip_runtime.h>

// Local context aggregation (DGCNN edge-conv style), MI355X.
// Pipeline (4 launches):
//   k_fp      : FUSED per-point pass: yG[n]=[F1|D1] (gather table, L2-fit/batch),
//               yC[n]=[Fc|Dc], xneg=-0.5|x|^2, split-bf16 hl[n][hi96|lo96], xT[n][96].
//   k_dist    : FUSED MFMA score + per-half top-24. R14: amdgpu_waves_per_eu(3,4)
//               stops the backend's occupancy-chasing remat (R9-R13 all compiled to
//               VGPR<=64 with reloads; runtime occupancy never exceeded ~4 w/SIMD).
//   k_selstats: FUSED f64 re-rank (top-20 -> idx) + BN norm statistics.
//   k_out     : BN scale/shift inlined + gather + directional leaky act + mean over k.
// ws usage: ~42 MB fixed.

namespace {
constexpr int BB = 4;
constexpr int NN = 4096;
constexpr int KK = 20;
constexpr int CC = 96;      // 32 features x 3 dims
constexpr int OO = 32;
constexpr int PTS = BB * NN;
constexpr int LT = 12;      // per-class top list depth (class = 128 cands)
constexpr int TCAND = 24;   // per-half candidates kept
constexpr int NENT = 16 * LT;     // entries per row: 4 waves x 4 kl x 12 = 192
constexpr int NENT_PAD = 196;     // padded row stride (words)
}

using bf16x8 = __attribute__((ext_vector_type(8))) short;
using f32x4 = __attribute__((ext_vector_type(4))) float;

__device__ __forceinline__ unsigned short f2bf(float f) {
  unsigned u = __float_as_uint(f);
  return (unsigned short)((u + 0x7fff + ((u >> 16) & 1)) >> 16);
}
__device__ __forceinline__ float bf2f(unsigned short b) {
  return __uint_as_float((unsigned)b << 16);
}
__device__ __forceinline__ unsigned umax32(unsigned a, unsigned b) { return a > b ? a : b; }
__device__ __forceinline__ unsigned med3u(unsigned a, unsigned b, unsigned c) {
  unsigned d;
  asm("v_med3_u32 %0, %1, %2, %3" : "=v"(d) : "v"(a), "v"(b), "v"(c));
  return d;
}

// ---------------- kernel 1: fused per-point pass ----------------
__global__ __launch_bounds__(256) void k_fp(
    const float* __restrict__ x, const float* __restrict__ Wf,
    const float* __restrict__ Wd,
    float* __restrict__ yG, float* __restrict__ yC, float* __restrict__ xneg,
    unsigned short* __restrict__ hl, float* __restrict__ xT) {
  __shared__ float tile[CC][65];   // ~25 KB
  __shared__ float sW[4][32][32];  // 16 KB
  const int t = threadIdx.x;
  const int b = blockIdx.x >> 6;             // 64 blocks per batch
  const int n0 = (blockIdx.x & 63) * 64;
  for (int i = t; i < 2048; i += 256) {
    int o = i & 31, f = (i >> 5) & 31, which = i >> 10;
    const float* W = which ? Wd : Wf;
    float a1 = W[o * 64 + f], a2 = W[o * 64 + 32 + f];
    sW[which * 2 + 0][f][o] = a1;
    sW[which * 2 + 1][f][o] = a2 - a1;
  }
#pragma unroll
  for (int i = 0; i < 24; ++i) {
    int v = i * 256 + t;
    int c = v >> 6, nn = v & 63;
    tile[c][nn] = x[((size_t)b * CC + c) * NN + n0 + nn];
  }
  __syncthreads();

  // ---- split-bf16 table: hl rows [hi 96 | lo 96], 24 x 16B chunks per row ----
#pragma unroll
  for (int i = 0; i < 6; ++i) {
    int v = i * 256 + t;                    // 0..1535 over 64 rows x 24 chunks
    int row = v / 24, k8 = v % 24;
    unsigned hb[4];
    if (k8 < 12) {
      int c0 = k8 * 8;
#pragma unroll
      for (int j = 0; j < 4; ++j) {
        unsigned short l16 = f2bf(tile[c0 + 2 * j][row]);
        unsigned short h16 = f2bf(tile[c0 + 2 * j + 1][row]);
        hb[j] = (unsigned)l16 | ((unsigned)h16 << 16);
      }
    } else {
      int c0 = (k8 - 12) * 8;
#pragma unroll
      for (int j = 0; j < 4; ++j) {
        float f0 = tile[c0 + 2 * j][row], f1 = tile[c0 + 2 * j + 1][row];
        unsigned short h0 = f2bf(f0), h1 = f2bf(f1);
        unsigned short l0 = f2bf(f0 - bf2f(h0)), l1 = f2bf(f1 - bf2f(h1));
        hb[j] = (unsigned)l0 | ((unsigned)l1 << 16);
      }
    }
    *(uint4*)(hl + (size_t)(b * NN + n0 + row) * 192 + k8 * 8) =
        make_uint4(hb[0], hb[1], hb[2], hb[3]);
  }
  // xT rows: 96 f32 contiguous per point
#pragma unroll
  for (int i = 0; i < 6; ++i) {
    int v = i * 256 + t;
    int row = v / 24, q = v % 24;
    float4 o4;
    o4.x = tile[q * 4 + 0][row]; o4.y = tile[q * 4 + 1][row];
    o4.z = tile[q * 4 + 2][row]; o4.w = tile[q * 4 + 3][row];
    *(float4*)(xT + (size_t)(b * NN + n0 + row) * CC + q * 4) = o4;
  }

  // ---- transforms: thread (o=t&31, pg=t>>5) handles 8 points ----
  const int o = t & 31, pg = t >> 5;
  for (int pp = 0; pp < 8; ++pp) {
    const int pl = pg * 8 + pp;              // point 0..63
    float aF1[3] = {0.f, 0.f, 0.f}, aFc[3] = {0.f, 0.f, 0.f};
    float aD1[3] = {0.f, 0.f, 0.f}, aDc[3] = {0.f, 0.f, 0.f};
#pragma unroll
    for (int f = 0; f < 32; ++f) {
      float w0 = sW[0][f][o], w1 = sW[1][f][o];
      float w2 = sW[2][f][o], w3 = sW[3][f][o];
#pragma unroll
      for (int dd = 0; dd < 3; ++dd) {
        float v = tile[f * 3 + dd][pl];
        aF1[dd] = fmaf(w0, v, aF1[dd]);
        aFc[dd] = fmaf(w1, v, aFc[dd]);
        aD1[dd] = fmaf(w2, v, aD1[dd]);
        aDc[dd] = fmaf(w3, v, aDc[dd]);
      }
    }
    const size_t pt = (size_t)(b * NN + n0 + pl) * 192 + o * 3;
#pragma unroll
    for (int dd = 0; dd < 3; ++dd) {
      yG[pt + dd] = aF1[dd]; yG[pt + 96 + dd] = aD1[dd];
      yC[pt + dd] = aFc[dd]; yC[pt + 96 + dd] = aDc[dd];
    }
  }
  // xneg: one thread per point
  if (t < 64) {
    float s = 0.f;
#pragma unroll 8
    for (int c = 0; c < CC; ++c) { float v = tile[c][t]; s = fmaf(v, v, s); }
    xneg[b * NN + n0 + t] = -0.5f * s;
  }
}

// ---------------- kernel 2: FUSED MFMA score + per-half top-24 ----------------
// 2048 blocks x 256 thr (4 waves). xcd=wg&7: b=xcd&3, half=xcd>>2. q=wg>>3 -> 16 rows.
// Wave w scans [half*2048 + w*512, +512) over 8 m-tiles of 64 (unrolled x2).
// key = monotone(score)[31:12] | class[10:7] | (127-local)[6:0]  (unique in block).
// amdgpu_waves_per_eu(3,4): cap occupancy target at 4 waves/EU so the backend stops
// remat-squeezing into the 8-wave/64-VGPR tier (R9-R13: VGPR=44-64 + L2 reloads).
__global__ __launch_bounds__(256)
__attribute__((amdgpu_waves_per_eu(3, 4))) void k_dist(
    const unsigned short* __restrict__ hl, const float* __restrict__ xneg,
    unsigned* __restrict__ candbuf) {
  __shared__ unsigned sEnt[16][NENT_PAD];
  const int t = threadIdx.x, lane = t & 63, w = t >> 6;
  const int wg = blockIdx.x;
  const int xcd = wg & 7;
  const int b = xcd & 3;
  const int half = xcd >> 2;
  const int nbase = (wg >> 3) << 4;          // 0..4080, step 16
  const int hoff = half * 2048;
  const int coff = hoff + w * 512;           // this wave's candidate range
  const unsigned short* hb = hl + (size_t)b * NN * 192;
  const int kl = lane >> 4, pr = lane & 15;
  const int cls = w * 4 + kl;                // 0..15
  const unsigned clsbase = (unsigned)(cls << 7);

  // resident operand-B fragments: the block's 16 query rows (col axis)
  bf16x8 rHf[3], rLf[3];
#pragma unroll
  for (int kb = 0; kb < 3; ++kb) {
    const unsigned short* p = hb + (size_t)(nbase + pr) * 192 + (kb * 4 + kl) * 8;
    rHf[kb] = *(const bf16x8*)p;
    rLf[kb] = *(const bf16x8*)(p + 96);
  }

  unsigned ls[LT];
#pragma unroll
  for (int j = 0; j < LT; ++j) ls[j] = 0u;   // 0 == -inf key

  // strength-reduced bases: all inner-loop loads use compile-time immediate offsets
  const unsigned short* pw = hb + ((size_t)coff + pr) * 192 + (size_t)kl * 8;
  const float* px = xneg + (size_t)b * NN + coff + kl * 4;

#pragma unroll 2
  for (int mt = 0; mt < 8; ++mt) {
    const unsigned tagbase = clsbase | (unsigned)(127 - mt * 16);
    const unsigned short* pm = pw + (size_t)mt * (64 * 192);
    const float* pxm = px + mt * 64;
#pragma unroll
    for (int ca = 0; ca < 4; ++ca) {
      const unsigned short* pc = pm + ca * 3072;      // 16 rows * 192 shorts
      f32x4 acc = *(const f32x4*)(pxm + ca * 16);     // -0.5*|xm|^2 preloaded
      bf16x8 h0 = *(const bf16x8*)(pc);
      bf16x8 l0 = *(const bf16x8*)(pc + 96);
      bf16x8 h1 = *(const bf16x8*)(pc + 32);
      bf16x8 l1 = *(const bf16x8*)(pc + 128);
      bf16x8 h2 = *(const bf16x8*)(pc + 64);
      bf16x8 l2 = *(const bf16x8*)(pc + 160);
      // (candH+candL)·(rowH+rowL) ~= cH·rH + cL·rH + cH·rL  (lo·lo ~2^-16)
      acc = __builtin_amdgcn_mfma_f32_16x16x32_bf16(h0, rHf[0], acc, 0, 0, 0);
      acc = __builtin_amdgcn_mfma_f32_16x16x32_bf16(l0, rHf[0], acc, 0, 0, 0);
      acc = __builtin_amdgcn_mfma_f32_16x16x32_bf16(h0, rLf[0], acc, 0, 0, 0);
      acc = __builtin_amdgcn_mfma_f32_16x16x32_bf16(h1, rHf[1], acc, 0, 0, 0);
      acc = __builtin_amdgcn_mfma_f32_16x16x32_bf16(l1, rHf[1], acc, 0, 0, 0);
      acc = __builtin_amdgcn_mfma_f32_16x16x32_bf16(h1, rLf[1], acc, 0, 0, 0);
      acc = __builtin_amdgcn_mfma_f32_16x16x32_bf16(h2, rHf[2], acc, 0, 0, 0);
      acc = __builtin_amdgcn_mfma_f32_16x16x32_bf16(l2, rHf[2], acc, 0, 0, 0);
      acc = __builtin_amdgcn_mfma_f32_16x16x32_bf16(h2, rLf[2], acc, 0, 0, 0);
      // C/D: col(lane&15)=query row; row((lane>>4)*4+r)=candidate offset.
      const unsigned tag = tagbase - (unsigned)(ca * 4);
#pragma unroll
      for (int r = 0; r < 4; ++r) {
        unsigned sb = __float_as_uint(acc[r]);
        sb ^= ((unsigned)((int)sb >> 31)) | 0x80000000u;
        unsigned key = (sb & 0xFFFFF000u) | (tag - (unsigned)r);
        // in-place parallel sorted-desc insert via med3 (reads pre-insert state)
#pragma unroll
        for (int j = LT - 1; j >= 1; --j)
          ls[j] = med3u(ls[j - 1], ls[j], key);
        ls[0] = umax32(ls[0], key);
      }
    }
  }
  // dump per-lane sorted key lists: row pr, entries [cls*12 .. +12)
  {
    unsigned* dst = &sEnt[pr][cls * LT];
    *(uint4*)(dst + 0) = make_uint4(ls[0], ls[1], ls[2], ls[3]);
    *(uint4*)(dst + 4) = make_uint4(ls[4], ls[5], ls[6], ls[7]);
    *(uint4*)(dst + 8) = make_uint4(ls[8], ls[9], ls[10], ls[11]);
  }
  __syncthreads();

  // rank-count merge: wave w handles rows w*4..w*4+3; lane owns entries {lane+64c}.
  // Keys unique -> ranks 0..191 a permutation -> all 24 candbuf slots written.
#pragma unroll
  for (int rr = 0; rr < 4; ++rr) {
    const int row = w * 4 + rr;
    unsigned mine[3]; int rk[3] = {0, 0, 0};
#pragma unroll
    for (int c = 0; c < 3; ++c) mine[c] = sEnt[row][lane + 64 * c];
    for (int i4 = 0; i4 < NENT / 4; ++i4) {
      uint4 e = *(const uint4*)&sEnt[row][i4 * 4];
#pragma unroll
      for (int c = 0; c < 3; ++c) {
        rk[c] += (e.x > mine[c]) ? 1 : 0;
        rk[c] += (e.y > mine[c]) ? 1 : 0;
        rk[c] += (e.z > mine[c]) ? 1 : 0;
        rk[c] += (e.w > mine[c]) ? 1 : 0;
      }
    }
#pragma unroll
    for (int c = 0; c < 3; ++c) {
      if (rk[c] < TCAND) {
        unsigned low = mine[c] & 0x7FFu;
        int kcls = (int)(low >> 7);
        int loc = 127 - (int)(low & 127u);
        unsigned id = (unsigned)(hoff + (kcls >> 2) * 512 + (loc >> 4) * 64 +
                                 ((loc >> 2) & 3) * 16 + (kcls & 3) * 4 + (loc & 3));
        candbuf[(size_t)(b * NN + nbase + row) * 48 + half * 24 + rk[c]] = id;
      }
    }
  }
}

// ---------------- kernel 3: FUSED exact f64 top-20 + BN statistics ----------------
// 512 thr = 8 waves, 8 rows/block, grid PTS/8, XCD-swizzled (b=blk&3).
__global__ __launch_bounds__(512) void k_selstats(
    const unsigned* __restrict__ candbuf, const float* __restrict__ xT,
    const float* __restrict__ yG, const float* __restrict__ yC,
    int* __restrict__ idxout, double* __restrict__ stats) {
  __shared__ int sTop[8][KK];
  __shared__ float rs1[8][32], rs2[8][32];
  const int t = threadIdx.x, lane = t & 63, w = t >> 6;
  const int b = blockIdx.x & 3;
  const int n = (blockIdx.x >> 2) * 8 + w;
  const int row = b * NN + n;
  const unsigned* cp = candbuf + (size_t)row * 48;
  const int hf = lane & 1;
  unsigned long long k0, k1; int c0, c1;
#pragma unroll
  for (int pass = 0; pass < 2; ++pass) {
    const int ci = pass * 24 + ((lane < 48) ? (lane >> 1) : 23);
    const int mycand = (int)cp[ci];
    const float* xm = xT + ((size_t)b * NN + mycand) * CC + hf * 48;
    const float* xr = xT + ((size_t)b * NN + n) * CC + hf * 48;
    double dot = 0.0, m2 = 0.0;
#pragma unroll 4
    for (int j = 0; j < 12; ++j) {
      float4 a = *(const float4*)&xm[j * 4];
      float4 q = *(const float4*)&xr[j * 4];
      dot = fma((double)q.x, (double)a.x, dot); m2 = fma((double)a.x, (double)a.x, m2);
      dot = fma((double)q.y, (double)a.y, dot); m2 = fma((double)a.y, (double)a.y, m2);
      dot = fma((double)q.z, (double)a.z, dot); m2 = fma((double)a.z, (double)a.z, m2);
      dot = fma((double)q.w, (double)a.w, dot); m2 = fma((double)a.w, (double)a.w, m2);
    }
    dot += __shfl_xor(dot, 1);
    m2 += __shfl_xor(m2, 1);
    double sc = 2.0 * dot - m2;
    unsigned long long bits = (unsigned long long)__double_as_longlong(sc);
    bits ^= ((unsigned long long)((long long)bits >> 63)) | 0x8000000000000000ull;
    unsigned long long key = (bits & ~0xFFFull) | (unsigned long long)(4095 - mycand);
    if (pass == 0) { k0 = key; c0 = mycand; } else { k1 = key; c1 = mycand; }
  }
  int r0c = 0, r1c = 0;
#pragma unroll
  for (int j = 0; j < 24; ++j) {
    unsigned long long a = __shfl(k0, j * 2);
    unsigned long long bb = __shfl(k1, j * 2);
    r0c += (a > k0) ? 1 : 0; r0c += (bb > k0) ? 1 : 0;
    r1c += (a > k1) ? 1 : 0; r1c += (bb > k1) ? 1 : 0;
  }
  if (lane < 48 && hf == 0) {
    if (r0c < KK) { idxout[(size_t)row * KK + r0c] = c0; sTop[w][r0c] = c0; }
    if (r1c < KK) { idxout[(size_t)row * KK + r1c] = c1; sTop[w][r1c] = c1; }
  }
  __builtin_amdgcn_wave_barrier();  // same-wave LDS write->read fence (compile-time)

  // ---- phase B: norm statistics for this row ----
  const int o = lane & 31, kh = lane >> 5;
  const size_t cb = (size_t)row * 192 + o * 3;
  const float pc0 = yC[cb], pc1 = yC[cb + 1], pc2 = yC[cb + 2];
  float s1 = 0.f, s2 = 0.f;
#pragma unroll
  for (int j = 0; j < 10; ++j) {
    int m = sTop[w][2 * j + kh];
    size_t a = ((size_t)b * NN + m) * 192 + o * 3;
    float p0 = yG[a] + pc0, p1 = yG[a + 1] + pc1, p2 = yG[a + 2] + pc2;
    float nr = sqrtf(p0 * p0 + p1 * p1 + p2 * p2) + 1e-6f;
    s1 += nr; s2 = fmaf(nr, nr, s2);
  }
  s1 += __shfl_xor(s1, 32);
  s2 += __shfl_xor(s2, 32);
  if (lane < 32) { rs1[w][o] = s1; rs2[w][o] = s2; }
  __syncthreads();
  if (t < 32) {
    float a1 = 0.f, a2 = 0.f;
#pragma unroll
    for (int ww = 0; ww < 8; ++ww) { a1 += rs1[ww][t]; a2 += rs2[ww][t]; }
    atomicAdd(&stats[t], (double)a1);
    atomicAdd(&stats[32 + t], (double)a2);
  }
}

// ---------------- kernel 4: gather + activation + mean over k (BN inlined) ----------------
__global__ __launch_bounds__(256) void k_out(
    const float* __restrict__ yG, const float* __restrict__ yC,
    const int* __restrict__ idx, const double* __restrict__ stats,
    const float* __restrict__ gamma, const float* __restrict__ beta,
    float* __restrict__ out) {
  __shared__ float sS[64];
  const int t = threadIdx.x, o = t & 31, nl = t >> 5;
  if (t < 32) {
    const double M = (double)BB * NN * KK;
    double mean = stats[t] / M;
    double var = stats[32 + t] / M - mean * mean;
    double inv = 1.0 / sqrt(var + 1e-5);
    sS[t] = (float)((double)gamma[t] * inv);
    sS[32 + t] = (float)((double)beta[t] - mean * (double)gamma[t] * inv);
  }
  __syncthreads();
  const int b = blockIdx.x & 3;
  const int n = (blockIdx.x >> 2) * 8 + nl;
  const size_t cb = (size_t)(b * NN + n) * 192 + o * 3;
  const float pc0 = yC[cb], pc1 = yC[cb + 1], pc2 = yC[cb + 2];
  const float dc0 = yC[cb + 96], dc1 = yC[cb + 97], dc2 = yC[cb + 98];
  const float sc = sS[o], sh = sS[32 + o];
  const int* ip = idx + (size_t)(b * NN + n) * KK;
  float a0 = 0.f, a1 = 0.f, a2 = 0.f;
  for (int k = 0; k < KK; ++k) {
    int m = ip[k];
    size_t a = (size_t)(b * NN + m) * 192 + o * 3;
    float p0 = yG[a] + pc0, p1 = yG[a + 1] + pc1, p2 = yG[a + 2] + pc2;
    float d0 = yG[a + 96] + dc0, d1 = yG[a + 97] + dc1, d2 = yG[a + 98] + dc2;
    float nr = sqrtf(p0 * p0 + p1 * p1 + p2 * p2) + 1e-6f;
    float f = (sc * nr + sh) / nr;
    p0 *= f; p1 *= f; p2 *= f;
    float dt = p0 * d0 + p1 * d1 + p2 * d2;
    float w8 = (dt >= 0.f) ? 0.f : 0.8f * dt / (d0 * d0 + d1 * d1 + d2 * d2 + 1e-6f);
    a0 += p0 - w8 * d0; a1 += p1 - w8 * d1; a2 += p2 - w8 * d2;
  }
  const float inv = 1.f / (float)KK;
  const size_t ob = ((size_t)(b * OO + o) * 3) * NN + n;
  out[ob] = a0 * inv; out[ob + NN] = a1 * inv; out[ob + 2 * NN] = a2 * inv;
}

extern "C" void kernel_launch(void* const* d_in, const int* in_sizes, int n_in,
                              void* d_out, int out_size, void* d_ws, size_t ws_size,
                              hipStream_t stream) {
  (void)in_sizes; (void)n_in; (void)out_size;
  const float* x = (const float*)d_in[0];
  const float* Wf = (const float*)d_in[1];
  const float* Wd = (const float*)d_in[2];
  const float* gamma = (const float*)d_in[3];
  const float* beta = (const float*)d_in[4];
  float* out = (float*)d_out;

  char* ws = (char*)d_ws;
  size_t off = 0;
  auto alloc = [&](size_t bytes) -> void* {
    void* p = ws + off;
    off += (bytes + 255) & ~(size_t)255;
    return p;
  };
  float* yG = (float*)alloc((size_t)PTS * 192 * 4);
  float* yC = (float*)alloc((size_t)PTS * 192 * 4);
  float* xneg = (float*)alloc((size_t)PTS * 4);
  int* idx   = (int*)alloc((size_t)PTS * KK * 4);
  double* stats = (double*)alloc(64 * 8);
  unsigned short* hl = (unsigned short*)alloc((size_t)PTS * 192 * 2);
  float* xT  = (float*)alloc((size_t)PTS * CC * 4);
  unsigned* candbuf = (unsigned*)alloc((size_t)PTS * 48 * 4);
  if (ws_size < off) return;

  hipMemsetAsync(stats, 0, 64 * 8, stream);
  k_fp<<<dim3(PTS / 64), dim3(256), 0, stream>>>(x, Wf, Wd, yG, yC, xneg, hl, xT);
  k_dist<<<dim3(BB * NN / 16 * 2), dim3(256), 0, stream>>>(hl, xneg, candbuf);
  k_selstats<<<dim3(PTS / 8), dim3(512), 0, stream>>>(candbuf, xT, yG, yC, idx, stats);
  k_out<<<dim3(PTS / 8), dim3(256), 0, stream>>>(yG, yC, idx, stats, gamma, beta, out);
}

// Round 15
// 317.445 us; speedup vs baseline: 1.4941x; 1.0238x over previous
//
#include <hip/hip_runtime.h>

// Local context aggregation (DGCNN edge-conv style), MI355X.
// Pipeline (4 launches):
//   k_fp      : FUSED per-point pass: yG[n]=[F1|D1] (gather table, L2-fit/batch),
//               yC[n]=[Fc|Dc], xneg=-0.5|x|^2, split-bf16 hl[n][hi96|lo96], xT[n][96].
//   k_dist    : FUSED MFMA score + per-half top-24. R15: explicit register
//               double-buffer prefetch of candidate fragments (R14 counters: 224 loads
//               x ~250cy L2 latency fully exposed = the missing 57k cyc/wave; compiler
//               never pipelined on its own at any register budget R9-R14).
//   k_selstats: FUSED f64 re-rank (top-20 -> idx) + BN norm statistics.
//   k_out     : BN scale/shift inlined + gather + directional leaky act + mean over k.
// ws usage: ~42 MB fixed.

namespace {
constexpr int BB = 4;
constexpr int NN = 4096;
constexpr int KK = 20;
constexpr int CC = 96;      // 32 features x 3 dims
constexpr int OO = 32;
constexpr int PTS = BB * NN;
constexpr int LT = 12;      // per-class top list depth (class = 128 cands)
constexpr int TCAND = 24;   // per-half candidates kept
constexpr int NENT = 16 * LT;     // entries per row: 4 waves x 4 kl x 12 = 192
constexpr int NENT_PAD = 196;     // padded row stride (words)
}

using bf16x8 = __attribute__((ext_vector_type(8))) short;
using f32x4 = __attribute__((ext_vector_type(4))) float;

__device__ __forceinline__ unsigned short f2bf(float f) {
  unsigned u = __float_as_uint(f);
  return (unsigned short)((u + 0x7fff + ((u >> 16) & 1)) >> 16);
}
__device__ __forceinline__ float bf2f(unsigned short b) {
  return __uint_as_float((unsigned)b << 16);
}
__device__ __forceinline__ unsigned umax32(unsigned a, unsigned b) { return a > b ? a : b; }
__device__ __forceinline__ unsigned med3u(unsigned a, unsigned b, unsigned c) {
  unsigned d;
  asm("v_med3_u32 %0, %1, %2, %3" : "=v"(d) : "v"(a), "v"(b), "v"(c));
  return d;
}

// ---------------- kernel 1: fused per-point pass ----------------
__global__ __launch_bounds__(256) void k_fp(
    const float* __restrict__ x, const float* __restrict__ Wf,
    const float* __restrict__ Wd,
    float* __restrict__ yG, float* __restrict__ yC, float* __restrict__ xneg,
    unsigned short* __restrict__ hl, float* __restrict__ xT) {
  __shared__ float tile[CC][65];   // ~25 KB
  __shared__ float sW[4][32][32];  // 16 KB
  const int t = threadIdx.x;
  const int b = blockIdx.x >> 6;             // 64 blocks per batch
  const int n0 = (blockIdx.x & 63) * 64;
  for (int i = t; i < 2048; i += 256) {
    int o = i & 31, f = (i >> 5) & 31, which = i >> 10;
    const float* W = which ? Wd : Wf;
    float a1 = W[o * 64 + f], a2 = W[o * 64 + 32 + f];
    sW[which * 2 + 0][f][o] = a1;
    sW[which * 2 + 1][f][o] = a2 - a1;
  }
#pragma unroll
  for (int i = 0; i < 24; ++i) {
    int v = i * 256 + t;
    int c = v >> 6, nn = v & 63;
    tile[c][nn] = x[((size_t)b * CC + c) * NN + n0 + nn];
  }
  __syncthreads();

  // ---- split-bf16 table: hl rows [hi 96 | lo 96], 24 x 16B chunks per row ----
#pragma unroll
  for (int i = 0; i < 6; ++i) {
    int v = i * 256 + t;                    // 0..1535 over 64 rows x 24 chunks
    int row = v / 24, k8 = v % 24;
    unsigned hb[4];
    if (k8 < 12) {
      int c0 = k8 * 8;
#pragma unroll
      for (int j = 0; j < 4; ++j) {
        unsigned short l16 = f2bf(tile[c0 + 2 * j][row]);
        unsigned short h16 = f2bf(tile[c0 + 2 * j + 1][row]);
        hb[j] = (unsigned)l16 | ((unsigned)h16 << 16);
      }
    } else {
      int c0 = (k8 - 12) * 8;
#pragma unroll
      for (int j = 0; j < 4; ++j) {
        float f0 = tile[c0 + 2 * j][row], f1 = tile[c0 + 2 * j + 1][row];
        unsigned short h0 = f2bf(f0), h1 = f2bf(f1);
        unsigned short l0 = f2bf(f0 - bf2f(h0)), l1 = f2bf(f1 - bf2f(h1));
        hb[j] = (unsigned)l0 | ((unsigned)l1 << 16);
      }
    }
    *(uint4*)(hl + (size_t)(b * NN + n0 + row) * 192 + k8 * 8) =
        make_uint4(hb[0], hb[1], hb[2], hb[3]);
  }
  // xT rows: 96 f32 contiguous per point
#pragma unroll
  for (int i = 0; i < 6; ++i) {
    int v = i * 256 + t;
    int row = v / 24, q = v % 24;
    float4 o4;
    o4.x = tile[q * 4 + 0][row]; o4.y = tile[q * 4 + 1][row];
    o4.z = tile[q * 4 + 2][row]; o4.w = tile[q * 4 + 3][row];
    *(float4*)(xT + (size_t)(b * NN + n0 + row) * CC + q * 4) = o4;
  }

  // ---- transforms: thread (o=t&31, pg=t>>5) handles 8 points ----
  const int o = t & 31, pg = t >> 5;
  for (int pp = 0; pp < 8; ++pp) {
    const int pl = pg * 8 + pp;              // point 0..63
    float aF1[3] = {0.f, 0.f, 0.f}, aFc[3] = {0.f, 0.f, 0.f};
    float aD1[3] = {0.f, 0.f, 0.f}, aDc[3] = {0.f, 0.f, 0.f};
#pragma unroll
    for (int f = 0; f < 32; ++f) {
      float w0 = sW[0][f][o], w1 = sW[1][f][o];
      float w2 = sW[2][f][o], w3 = sW[3][f][o];
#pragma unroll
      for (int dd = 0; dd < 3; ++dd) {
        float v = tile[f * 3 + dd][pl];
        aF1[dd] = fmaf(w0, v, aF1[dd]);
        aFc[dd] = fmaf(w1, v, aFc[dd]);
        aD1[dd] = fmaf(w2, v, aD1[dd]);
        aDc[dd] = fmaf(w3, v, aDc[dd]);
      }
    }
    const size_t pt = (size_t)(b * NN + n0 + pl) * 192 + o * 3;
#pragma unroll
    for (int dd = 0; dd < 3; ++dd) {
      yG[pt + dd] = aF1[dd]; yG[pt + 96 + dd] = aD1[dd];
      yC[pt + dd] = aFc[dd]; yC[pt + 96 + dd] = aDc[dd];
    }
  }
  // xneg: one thread per point
  if (t < 64) {
    float s = 0.f;
#pragma unroll 8
    for (int c = 0; c < CC; ++c) { float v = tile[c][t]; s = fmaf(v, v, s); }
    xneg[b * NN + n0 + t] = -0.5f * s;
  }
}

// ---------------- kernel 2: FUSED MFMA score + per-half top-24 ----------------
// 2048 blocks x 256 thr (4 waves). xcd=wg&7: b=xcd&3, half=xcd>>2. q=wg>>3 -> 16 rows.
// Wave w scans [half*2048 + w*512, +512): flat 32-step loop (idx = mt*4+ca),
// register double-buffer: LOAD(idx+1) issued BEFORE compute(idx) so ~430cy of
// MFMA+insert covers the ~250cy L2 latency of the next fragment group.
// key = monotone(score)[31:12] | class[10:7] | (127-local)[6:0]  (unique in block).
__global__ __launch_bounds__(256)
__attribute__((amdgpu_waves_per_eu(3, 4))) void k_dist(
    const unsigned short* __restrict__ hl, const float* __restrict__ xneg,
    unsigned* __restrict__ candbuf) {
  __shared__ unsigned sEnt[16][NENT_PAD];
  const int t = threadIdx.x, lane = t & 63, w = t >> 6;
  const int wg = blockIdx.x;
  const int xcd = wg & 7;
  const int b = xcd & 3;
  const int half = xcd >> 2;
  const int nbase = (wg >> 3) << 4;          // 0..4080, step 16
  const int hoff = half * 2048;
  const int coff = hoff + w * 512;           // this wave's candidate range
  const unsigned short* hb = hl + (size_t)b * NN * 192;
  const int kl = lane >> 4, pr = lane & 15;
  const int cls = w * 4 + kl;                // 0..15
  const unsigned clsbase = (unsigned)(cls << 7);

  // resident operand-B fragments: the block's 16 query rows (col axis)
  bf16x8 rHf[3], rLf[3];
#pragma unroll
  for (int kb = 0; kb < 3; ++kb) {
    const unsigned short* p = hb + (size_t)(nbase + pr) * 192 + (kb * 4 + kl) * 8;
    rHf[kb] = *(const bf16x8*)p;
    rLf[kb] = *(const bf16x8*)(p + 96);
  }

  unsigned ls[LT];
#pragma unroll
  for (int j = 0; j < LT; ++j) ls[j] = 0u;   // 0 == -inf key

  // bases: candidate group idx (0..31) lives at pw + idx*3072, xneg at px + idx*16
  const unsigned short* pw = hb + ((size_t)coff + pr) * 192 + (size_t)kl * 8;
  const float* px = xneg + (size_t)b * NN + coff + kl * 4;

  bf16x8 ch0, cl0, ch1, cl1, ch2, cl2;   // current fragment set
  f32x4 cxn;
  {
    ch0 = *(const bf16x8*)(pw);       cl0 = *(const bf16x8*)(pw + 96);
    ch1 = *(const bf16x8*)(pw + 32);  cl1 = *(const bf16x8*)(pw + 128);
    ch2 = *(const bf16x8*)(pw + 64);  cl2 = *(const bf16x8*)(pw + 160);
    cxn = *(const f32x4*)(px);
  }
#pragma unroll
  for (int idx = 0; idx < 32; ++idx) {
    // prefetch next group (clamped tail) BEFORE compute of current
    const int ni = (idx < 31) ? idx + 1 : 31;
    const unsigned short* pn = pw + (size_t)ni * 3072;
    bf16x8 nh0 = *(const bf16x8*)(pn);       bf16x8 nl0 = *(const bf16x8*)(pn + 96);
    bf16x8 nh1 = *(const bf16x8*)(pn + 32);  bf16x8 nl1 = *(const bf16x8*)(pn + 128);
    bf16x8 nh2 = *(const bf16x8*)(pn + 64);  bf16x8 nl2 = *(const bf16x8*)(pn + 160);
    f32x4 nxn = *(const f32x4*)(px + ni * 16);

    // compute current: (candH+candL)·(rowH+rowL) ~= cH·rH + cL·rH + cH·rL
    f32x4 acc = cxn;                          // -0.5*|xm|^2 preloaded
    acc = __builtin_amdgcn_mfma_f32_16x16x32_bf16(ch0, rHf[0], acc, 0, 0, 0);
    acc = __builtin_amdgcn_mfma_f32_16x16x32_bf16(cl0, rHf[0], acc, 0, 0, 0);
    acc = __builtin_amdgcn_mfma_f32_16x16x32_bf16(ch0, rLf[0], acc, 0, 0, 0);
    acc = __builtin_amdgcn_mfma_f32_16x16x32_bf16(ch1, rHf[1], acc, 0, 0, 0);
    acc = __builtin_amdgcn_mfma_f32_16x16x32_bf16(cl1, rHf[1], acc, 0, 0, 0);
    acc = __builtin_amdgcn_mfma_f32_16x16x32_bf16(ch1, rLf[1], acc, 0, 0, 0);
    acc = __builtin_amdgcn_mfma_f32_16x16x32_bf16(ch2, rHf[2], acc, 0, 0, 0);
    acc = __builtin_amdgcn_mfma_f32_16x16x32_bf16(cl2, rHf[2], acc, 0, 0, 0);
    acc = __builtin_amdgcn_mfma_f32_16x16x32_bf16(ch2, rLf[2], acc, 0, 0, 0);
    // C/D: col(lane&15)=query row; row((lane>>4)*4+r)=candidate offset.
    const unsigned tag = clsbase | (unsigned)(127 - idx * 4);
#pragma unroll
    for (int r = 0; r < 4; ++r) {
      unsigned sb = __float_as_uint(acc[r]);
      sb ^= ((unsigned)((int)sb >> 31)) | 0x80000000u;
      unsigned key = (sb & 0xFFFFF000u) | (tag - (unsigned)r);
      // in-place parallel sorted-desc insert via med3 (reads pre-insert state)
#pragma unroll
      for (int j = LT - 1; j >= 1; --j)
        ls[j] = med3u(ls[j - 1], ls[j], key);
      ls[0] = umax32(ls[0], key);
    }
    // rotate buffers
    ch0 = nh0; cl0 = nl0; ch1 = nh1; cl1 = nl1; ch2 = nh2; cl2 = nl2; cxn = nxn;
  }
  // dump per-lane sorted key lists: row pr, entries [cls*12 .. +12)
  {
    unsigned* dst = &sEnt[pr][cls * LT];
    *(uint4*)(dst + 0) = make_uint4(ls[0], ls[1], ls[2], ls[3]);
    *(uint4*)(dst + 4) = make_uint4(ls[4], ls[5], ls[6], ls[7]);
    *(uint4*)(dst + 8) = make_uint4(ls[8], ls[9], ls[10], ls[11]);
  }
  __syncthreads();

  // rank-count merge: wave w handles rows w*4..w*4+3; lane owns entries {lane+64c}.
  // Keys unique -> ranks 0..191 a permutation -> all 24 candbuf slots written.
#pragma unroll
  for (int rr = 0; rr < 4; ++rr) {
    const int row = w * 4 + rr;
    unsigned mine[3]; int rk[3] = {0, 0, 0};
#pragma unroll
    for (int c = 0; c < 3; ++c) mine[c] = sEnt[row][lane + 64 * c];
    for (int i4 = 0; i4 < NENT / 4; ++i4) {
      uint4 e = *(const uint4*)&sEnt[row][i4 * 4];
#pragma unroll
      for (int c = 0; c < 3; ++c) {
        rk[c] += (e.x > mine[c]) ? 1 : 0;
        rk[c] += (e.y > mine[c]) ? 1 : 0;
        rk[c] += (e.z > mine[c]) ? 1 : 0;
        rk[c] += (e.w > mine[c]) ? 1 : 0;
      }
    }
#pragma unroll
    for (int c = 0; c < 3; ++c) {
      if (rk[c] < TCAND) {
        unsigned low = mine[c] & 0x7FFu;
        int kcls = (int)(low >> 7);
        int loc = 127 - (int)(low & 127u);
        unsigned id = (unsigned)(hoff + (kcls >> 2) * 512 + (loc >> 4) * 64 +
                                 ((loc >> 2) & 3) * 16 + (kcls & 3) * 4 + (loc & 3));
        candbuf[(size_t)(b * NN + nbase + row) * 48 + half * 24 + rk[c]] = id;
      }
    }
  }
}

// ---------------- kernel 3: FUSED exact f64 top-20 + BN statistics ----------------
// 512 thr = 8 waves, 8 rows/block, grid PTS/8, XCD-swizzled (b=blk&3).
__global__ __launch_bounds__(512) void k_selstats(
    const unsigned* __restrict__ candbuf, const float* __restrict__ xT,
    const float* __restrict__ yG, const float* __restrict__ yC,
    int* __restrict__ idxout, double* __restrict__ stats) {
  __shared__ int sTop[8][KK];
  __shared__ float rs1[8][32], rs2[8][32];
  const int t = threadIdx.x, lane = t & 63, w = t >> 6;
  const int b = blockIdx.x & 3;
  const int n = (blockIdx.x >> 2) * 8 + w;
  const int row = b * NN + n;
  const unsigned* cp = candbuf + (size_t)row * 48;
  const int hf = lane & 1;
  unsigned long long k0, k1; int c0, c1;
#pragma unroll
  for (int pass = 0; pass < 2; ++pass) {
    const int ci = pass * 24 + ((lane < 48) ? (lane >> 1) : 23);
    const int mycand = (int)cp[ci];
    const float* xm = xT + ((size_t)b * NN + mycand) * CC + hf * 48;
    const float* xr = xT + ((size_t)b * NN + n) * CC + hf * 48;
    double dot = 0.0, m2 = 0.0;
#pragma unroll 4
    for (int j = 0; j < 12; ++j) {
      float4 a = *(const float4*)&xm[j * 4];
      float4 q = *(const float4*)&xr[j * 4];
      dot = fma((double)q.x, (double)a.x, dot); m2 = fma((double)a.x, (double)a.x, m2);
      dot = fma((double)q.y, (double)a.y, dot); m2 = fma((double)a.y, (double)a.y, m2);
      dot = fma((double)q.z, (double)a.z, dot); m2 = fma((double)a.z, (double)a.z, m2);
      dot = fma((double)q.w, (double)a.w, dot); m2 = fma((double)a.w, (double)a.w, m2);
    }
    dot += __shfl_xor(dot, 1);
    m2 += __shfl_xor(m2, 1);
    double sc = 2.0 * dot - m2;
    unsigned long long bits = (unsigned long long)__double_as_longlong(sc);
    bits ^= ((unsigned long long)((long long)bits >> 63)) | 0x8000000000000000ull;
    unsigned long long key = (bits & ~0xFFFull) | (unsigned long long)(4095 - mycand);
    if (pass == 0) { k0 = key; c0 = mycand; } else { k1 = key; c1 = mycand; }
  }
  int r0c = 0, r1c = 0;
#pragma unroll
  for (int j = 0; j < 24; ++j) {
    unsigned long long a = __shfl(k0, j * 2);
    unsigned long long bb = __shfl(k1, j * 2);
    r0c += (a > k0) ? 1 : 0; r0c += (bb > k0) ? 1 : 0;
    r1c += (a > k1) ? 1 : 0; r1c += (bb > k1) ? 1 : 0;
  }
  if (lane < 48 && hf == 0) {
    if (r0c < KK) { idxout[(size_t)row * KK + r0c] = c0; sTop[w][r0c] = c0; }
    if (r1c < KK) { idxout[(size_t)row * KK + r1c] = c1; sTop[w][r1c] = c1; }
  }
  __builtin_amdgcn_wave_barrier();  // same-wave LDS write->read fence (compile-time)

  // ---- phase B: norm statistics for this row ----
  const int o = lane & 31, kh = lane >> 5;
  const size_t cb = (size_t)row * 192 + o * 3;
  const float pc0 = yC[cb], pc1 = yC[cb + 1], pc2 = yC[cb + 2];
  float s1 = 0.f, s2 = 0.f;
#pragma unroll
  for (int j = 0; j < 10; ++j) {
    int m = sTop[w][2 * j + kh];
    size_t a = ((size_t)b * NN + m) * 192 + o * 3;
    float p0 = yG[a] + pc0, p1 = yG[a + 1] + pc1, p2 = yG[a + 2] + pc2;
    float nr = sqrtf(p0 * p0 + p1 * p1 + p2 * p2) + 1e-6f;
    s1 += nr; s2 = fmaf(nr, nr, s2);
  }
  s1 += __shfl_xor(s1, 32);
  s2 += __shfl_xor(s2, 32);
  if (lane < 32) { rs1[w][o] = s1; rs2[w][o] = s2; }
  __syncthreads();
  if (t < 32) {
    float a1 = 0.f, a2 = 0.f;
#pragma unroll
    for (int ww = 0; ww < 8; ++ww) { a1 += rs1[ww][t]; a2 += rs2[ww][t]; }
    atomicAdd(&stats[t], (double)a1);
    atomicAdd(&stats[32 + t], (double)a2);
  }
}

// ---------------- kernel 4: gather + activation + mean over k (BN inlined) ----------------
__global__ __launch_bounds__(256) void k_out(
    const float* __restrict__ yG, const float* __restrict__ yC,
    const int* __restrict__ idx, const double* __restrict__ stats,
    const float* __restrict__ gamma, const float* __restrict__ beta,
    float* __restrict__ out) {
  __shared__ float sS[64];
  const int t = threadIdx.x, o = t & 31, nl = t >> 5;
  if (t < 32) {
    const double M = (double)BB * NN * KK;
    double mean = stats[t] / M;
    double var = stats[32 + t] / M - mean * mean;
    double inv = 1.0 / sqrt(var + 1e-5);
    sS[t] = (float)((double)gamma[t] * inv);
    sS[32 + t] = (float)((double)beta[t] - mean * (double)gamma[t] * inv);
  }
  __syncthreads();
  const int b = blockIdx.x & 3;
  const int n = (blockIdx.x >> 2) * 8 + nl;
  const size_t cb = (size_t)(b * NN + n) * 192 + o * 3;
  const float pc0 = yC[cb], pc1 = yC[cb + 1], pc2 = yC[cb + 2];
  const float dc0 = yC[cb + 96], dc1 = yC[cb + 97], dc2 = yC[cb + 98];
  const float sc = sS[o], sh = sS[32 + o];
  const int* ip = idx + (size_t)(b * NN + n) * KK;
  float a0 = 0.f, a1 = 0.f, a2 = 0.f;
  for (int k = 0; k < KK; ++k) {
    int m = ip[k];
    size_t a = (size_t)(b * NN + m) * 192 + o * 3;
    float p0 = yG[a] + pc0, p1 = yG[a + 1] + pc1, p2 = yG[a + 2] + pc2;
    float d0 = yG[a + 96] + dc0, d1 = yG[a + 97] + dc1, d2 = yG[a + 98] + dc2;
    float nr = sqrtf(p0 * p0 + p1 * p1 + p2 * p2) + 1e-6f;
    float f = (sc * nr + sh) / nr;
    p0 *= f; p1 *= f; p2 *= f;
    float dt = p0 * d0 + p1 * d1 + p2 * d2;
    float w8 = (dt >= 0.f) ? 0.f : 0.8f * dt / (d0 * d0 + d1 * d1 + d2 * d2 + 1e-6f);
    a0 += p0 - w8 * d0; a1 += p1 - w8 * d1; a2 += p2 - w8 * d2;
  }
  const float inv = 1.f / (float)KK;
  const size_t ob = ((size_t)(b * OO + o) * 3) * NN + n;
  out[ob] = a0 * inv; out[ob + NN] = a1 * inv; out[ob + 2 * NN] = a2 * inv;
}

extern "C" void kernel_launch(void* const* d_in, const int* in_sizes, int n_in,
                              void* d_out, int out_size, void* d_ws, size_t ws_size,
                              hipStream_t stream) {
  (void)in_sizes; (void)n_in; (void)out_size;
  const float* x = (const float*)d_in[0];
  const float* Wf = (const float*)d_in[1];
  const float* Wd = (const float*)d_in[2];
  const float* gamma = (const float*)d_in[3];
  const float* beta = (const float*)d_in[4];
  float* out = (float*)d_out;

  char* ws = (char*)d_ws;
  size_t off = 0;
  auto alloc = [&](size_t bytes) -> void* {
    void* p = ws + off;
    off += (bytes + 255) & ~(size_t)255;
    return p;
  };
  float* yG = (float*)alloc((size_t)PTS * 192 * 4);
  float* yC = (float*)alloc((size_t)PTS * 192 * 4);
  float* xneg = (float*)alloc((size_t)PTS * 4);
  int* idx   = (int*)alloc((size_t)PTS * KK * 4);
  double* stats = (double*)alloc(64 * 8);
  unsigned short* hl = (unsigned short*)alloc((size_t)PTS * 192 * 2);
  float* xT  = (float*)alloc((size_t)PTS * CC * 4);
  unsigned* candbuf = (unsigned*)alloc((size_t)PTS * 48 * 4);
  if (ws_size < off) return;

  hipMemsetAsync(stats, 0, 64 * 8, stream);
  k_fp<<<dim3(PTS / 64), dim3(256), 0, stream>>>(x, Wf, Wd, yG, yC, xneg, hl, xT);
  k_dist<<<dim3(BB * NN / 16 * 2), dim3(256), 0, stream>>>(hl, xneg, candbuf);
  k_selstats<<<dim3(PTS / 8), dim3(512), 0, stream>>>(candbuf, xT, yG, yC, idx, stats);
  k_out<<<dim3(PTS / 8), dim3(256), 0, stream>>>(yG, yC, idx, stats, gamma, beta, out);
}

// Round 16
// 315.848 us; speedup vs baseline: 1.5017x; 1.0051x over previous
//
#include <hip/hip_runtime.h>

// Local context aggregation (DGCNN edge-conv style), MI355X.
// Pipeline (4 launches):
//   k_fp      : FUSED per-point pass: yG[n]=[F1|D1] (gather table, L2-fit/batch),
//               yC[n]=[Fc|Dc], xneg=-0.5|x|^2, split-bf16 hl[n][hi96|lo96], xT[n][96].
//   k_dist    : FUSED MFMA score + per-half top-24. R16: sched_barrier(0) between
//               prefetch-load group and compute group each iteration — R15's source
//               prefetch was sunk back to use points by the scheduler (VGPR stayed 52);
//               the barrier pins load-issue ahead of the ~430cy compute window.
//   k_selstats: FUSED f64 re-rank (top-20 -> idx) + BN norm statistics.
//   k_out     : BN scale/shift inlined + gather + directional leaky act + mean over k.
// ws usage: ~42 MB fixed.

namespace {
constexpr int BB = 4;
constexpr int NN = 4096;
constexpr int KK = 20;
constexpr int CC = 96;      // 32 features x 3 dims
constexpr int OO = 32;
constexpr int PTS = BB * NN;
constexpr int LT = 12;      // per-class top list depth (class = 128 cands)
constexpr int TCAND = 24;   // per-half candidates kept
constexpr int NENT = 16 * LT;     // entries per row: 4 waves x 4 kl x 12 = 192
constexpr int NENT_PAD = 196;     // padded row stride (words)
}

using bf16x8 = __attribute__((ext_vector_type(8))) short;
using f32x4 = __attribute__((ext_vector_type(4))) float;

__device__ __forceinline__ unsigned short f2bf(float f) {
  unsigned u = __float_as_uint(f);
  return (unsigned short)((u + 0x7fff + ((u >> 16) & 1)) >> 16);
}
__device__ __forceinline__ float bf2f(unsigned short b) {
  return __uint_as_float((unsigned)b << 16);
}
__device__ __forceinline__ unsigned umax32(unsigned a, unsigned b) { return a > b ? a : b; }
__device__ __forceinline__ unsigned med3u(unsigned a, unsigned b, unsigned c) {
  unsigned d;
  asm("v_med3_u32 %0, %1, %2, %3" : "=v"(d) : "v"(a), "v"(b), "v"(c));
  return d;
}

// ---------------- kernel 1: fused per-point pass ----------------
__global__ __launch_bounds__(256) void k_fp(
    const float* __restrict__ x, const float* __restrict__ Wf,
    const float* __restrict__ Wd,
    float* __restrict__ yG, float* __restrict__ yC, float* __restrict__ xneg,
    unsigned short* __restrict__ hl, float* __restrict__ xT) {
  __shared__ float tile[CC][65];   // ~25 KB
  __shared__ float sW[4][32][32];  // 16 KB
  const int t = threadIdx.x;
  const int b = blockIdx.x >> 6;             // 64 blocks per batch
  const int n0 = (blockIdx.x & 63) * 64;
  for (int i = t; i < 2048; i += 256) {
    int o = i & 31, f = (i >> 5) & 31, which = i >> 10;
    const float* W = which ? Wd : Wf;
    float a1 = W[o * 64 + f], a2 = W[o * 64 + 32 + f];
    sW[which * 2 + 0][f][o] = a1;
    sW[which * 2 + 1][f][o] = a2 - a1;
  }
#pragma unroll
  for (int i = 0; i < 24; ++i) {
    int v = i * 256 + t;
    int c = v >> 6, nn = v & 63;
    tile[c][nn] = x[((size_t)b * CC + c) * NN + n0 + nn];
  }
  __syncthreads();

  // ---- split-bf16 table: hl rows [hi 96 | lo 96], 24 x 16B chunks per row ----
#pragma unroll
  for (int i = 0; i < 6; ++i) {
    int v = i * 256 + t;                    // 0..1535 over 64 rows x 24 chunks
    int row = v / 24, k8 = v % 24;
    unsigned hb[4];
    if (k8 < 12) {
      int c0 = k8 * 8;
#pragma unroll
      for (int j = 0; j < 4; ++j) {
        unsigned short l16 = f2bf(tile[c0 + 2 * j][row]);
        unsigned short h16 = f2bf(tile[c0 + 2 * j + 1][row]);
        hb[j] = (unsigned)l16 | ((unsigned)h16 << 16);
      }
    } else {
      int c0 = (k8 - 12) * 8;
#pragma unroll
      for (int j = 0; j < 4; ++j) {
        float f0 = tile[c0 + 2 * j][row], f1 = tile[c0 + 2 * j + 1][row];
        unsigned short h0 = f2bf(f0), h1 = f2bf(f1);
        unsigned short l0 = f2bf(f0 - bf2f(h0)), l1 = f2bf(f1 - bf2f(h1));
        hb[j] = (unsigned)l0 | ((unsigned)l1 << 16);
      }
    }
    *(uint4*)(hl + (size_t)(b * NN + n0 + row) * 192 + k8 * 8) =
        make_uint4(hb[0], hb[1], hb[2], hb[3]);
  }
  // xT rows: 96 f32 contiguous per point
#pragma unroll
  for (int i = 0; i < 6; ++i) {
    int v = i * 256 + t;
    int row = v / 24, q = v % 24;
    float4 o4;
    o4.x = tile[q * 4 + 0][row]; o4.y = tile[q * 4 + 1][row];
    o4.z = tile[q * 4 + 2][row]; o4.w = tile[q * 4 + 3][row];
    *(float4*)(xT + (size_t)(b * NN + n0 + row) * CC + q * 4) = o4;
  }

  // ---- transforms: thread (o=t&31, pg=t>>5) handles 8 points ----
  const int o = t & 31, pg = t >> 5;
  for (int pp = 0; pp < 8; ++pp) {
    const int pl = pg * 8 + pp;              // point 0..63
    float aF1[3] = {0.f, 0.f, 0.f}, aFc[3] = {0.f, 0.f, 0.f};
    float aD1[3] = {0.f, 0.f, 0.f}, aDc[3] = {0.f, 0.f, 0.f};
#pragma unroll
    for (int f = 0; f < 32; ++f) {
      float w0 = sW[0][f][o], w1 = sW[1][f][o];
      float w2 = sW[2][f][o], w3 = sW[3][f][o];
#pragma unroll
      for (int dd = 0; dd < 3; ++dd) {
        float v = tile[f * 3 + dd][pl];
        aF1[dd] = fmaf(w0, v, aF1[dd]);
        aFc[dd] = fmaf(w1, v, aFc[dd]);
        aD1[dd] = fmaf(w2, v, aD1[dd]);
        aDc[dd] = fmaf(w3, v, aDc[dd]);
      }
    }
    const size_t pt = (size_t)(b * NN + n0 + pl) * 192 + o * 3;
#pragma unroll
    for (int dd = 0; dd < 3; ++dd) {
      yG[pt + dd] = aF1[dd]; yG[pt + 96 + dd] = aD1[dd];
      yC[pt + dd] = aFc[dd]; yC[pt + 96 + dd] = aDc[dd];
    }
  }
  // xneg: one thread per point
  if (t < 64) {
    float s = 0.f;
#pragma unroll 8
    for (int c = 0; c < CC; ++c) { float v = tile[c][t]; s = fmaf(v, v, s); }
    xneg[b * NN + n0 + t] = -0.5f * s;
  }
}

// ---------------- kernel 2: FUSED MFMA score + per-half top-24 ----------------
// 2048 blocks x 256 thr (4 waves). xcd=wg&7: b=xcd&3, half=xcd>>2. q=wg>>3 -> 16 rows.
// Wave w scans [half*2048 + w*512, +512): flat 32-step loop, register double-buffer,
// sched_barrier(0) pins prefetch-issue ahead of compute (scheduler sank it in R15).
// key = monotone(score)[31:12] | class[10:7] | (127-local)[6:0]  (unique in block).
__global__ __launch_bounds__(256)
__attribute__((amdgpu_waves_per_eu(3, 4))) void k_dist(
    const unsigned short* __restrict__ hl, const float* __restrict__ xneg,
    unsigned* __restrict__ candbuf) {
  __shared__ unsigned sEnt[16][NENT_PAD];
  const int t = threadIdx.x, lane = t & 63, w = t >> 6;
  const int wg = blockIdx.x;
  const int xcd = wg & 7;
  const int b = xcd & 3;
  const int half = xcd >> 2;
  const int nbase = (wg >> 3) << 4;          // 0..4080, step 16
  const int hoff = half * 2048;
  const int coff = hoff + w * 512;           // this wave's candidate range
  const unsigned short* hb = hl + (size_t)b * NN * 192;
  const int kl = lane >> 4, pr = lane & 15;
  const int cls = w * 4 + kl;                // 0..15
  const unsigned clsbase = (unsigned)(cls << 7);

  // resident operand-B fragments: the block's 16 query rows (col axis)
  bf16x8 rHf[3], rLf[3];
#pragma unroll
  for (int kb = 0; kb < 3; ++kb) {
    const unsigned short* p = hb + (size_t)(nbase + pr) * 192 + (kb * 4 + kl) * 8;
    rHf[kb] = *(const bf16x8*)p;
    rLf[kb] = *(const bf16x8*)(p + 96);
  }

  unsigned ls[LT];
#pragma unroll
  for (int j = 0; j < LT; ++j) ls[j] = 0u;   // 0 == -inf key

  // bases: candidate group idx (0..31) lives at pw + idx*3072, xneg at px + idx*16
  const unsigned short* pw = hb + ((size_t)coff + pr) * 192 + (size_t)kl * 8;
  const float* px = xneg + (size_t)b * NN + coff + kl * 4;

  bf16x8 ch0, cl0, ch1, cl1, ch2, cl2;   // current fragment set
  f32x4 cxn;
  {
    ch0 = *(const bf16x8*)(pw);       cl0 = *(const bf16x8*)(pw + 96);
    ch1 = *(const bf16x8*)(pw + 32);  cl1 = *(const bf16x8*)(pw + 128);
    ch2 = *(const bf16x8*)(pw + 64);  cl2 = *(const bf16x8*)(pw + 160);
    cxn = *(const f32x4*)(px);
  }
#pragma unroll
  for (int idx = 0; idx < 32; ++idx) {
    // prefetch next group (clamped tail)
    const int ni = (idx < 31) ? idx + 1 : 31;
    const unsigned short* pn = pw + (size_t)ni * 3072;
    bf16x8 nh0 = *(const bf16x8*)(pn);       bf16x8 nl0 = *(const bf16x8*)(pn + 96);
    bf16x8 nh1 = *(const bf16x8*)(pn + 32);  bf16x8 nl1 = *(const bf16x8*)(pn + 128);
    bf16x8 nh2 = *(const bf16x8*)(pn + 64);  bf16x8 nl2 = *(const bf16x8*)(pn + 160);
    f32x4 nxn = *(const f32x4*)(px + ni * 16);
    // pin: prefetch loads above must be ISSUED before the compute below
    __builtin_amdgcn_sched_barrier(0);

    // compute current: (candH+candL)·(rowH+rowL) ~= cH·rH + cL·rH + cH·rL
    f32x4 acc = cxn;                          // -0.5*|xm|^2 preloaded
    acc = __builtin_amdgcn_mfma_f32_16x16x32_bf16(ch0, rHf[0], acc, 0, 0, 0);
    acc = __builtin_amdgcn_mfma_f32_16x16x32_bf16(cl0, rHf[0], acc, 0, 0, 0);
    acc = __builtin_amdgcn_mfma_f32_16x16x32_bf16(ch0, rLf[0], acc, 0, 0, 0);
    acc = __builtin_amdgcn_mfma_f32_16x16x32_bf16(ch1, rHf[1], acc, 0, 0, 0);
    acc = __builtin_amdgcn_mfma_f32_16x16x32_bf16(cl1, rHf[1], acc, 0, 0, 0);
    acc = __builtin_amdgcn_mfma_f32_16x16x32_bf16(ch1, rLf[1], acc, 0, 0, 0);
    acc = __builtin_amdgcn_mfma_f32_16x16x32_bf16(ch2, rHf[2], acc, 0, 0, 0);
    acc = __builtin_amdgcn_mfma_f32_16x16x32_bf16(cl2, rHf[2], acc, 0, 0, 0);
    acc = __builtin_amdgcn_mfma_f32_16x16x32_bf16(ch2, rLf[2], acc, 0, 0, 0);
    // C/D: col(lane&15)=query row; row((lane>>4)*4+r)=candidate offset.
    const unsigned tag = clsbase | (unsigned)(127 - idx * 4);
#pragma unroll
    for (int r = 0; r < 4; ++r) {
      unsigned sb = __float_as_uint(acc[r]);
      sb ^= ((unsigned)((int)sb >> 31)) | 0x80000000u;
      unsigned key = (sb & 0xFFFFF000u) | (tag - (unsigned)r);
      // in-place parallel sorted-desc insert via med3 (reads pre-insert state)
#pragma unroll
      for (int j = LT - 1; j >= 1; --j)
        ls[j] = med3u(ls[j - 1], ls[j], key);
      ls[0] = umax32(ls[0], key);
    }
    // rotate buffers (free after full unroll: pure renaming)
    ch0 = nh0; cl0 = nl0; ch1 = nh1; cl1 = nl1; ch2 = nh2; cl2 = nl2; cxn = nxn;
  }
  // dump per-lane sorted key lists: row pr, entries [cls*12 .. +12)
  {
    unsigned* dst = &sEnt[pr][cls * LT];
    *(uint4*)(dst + 0) = make_uint4(ls[0], ls[1], ls[2], ls[3]);
    *(uint4*)(dst + 4) = make_uint4(ls[4], ls[5], ls[6], ls[7]);
    *(uint4*)(dst + 8) = make_uint4(ls[8], ls[9], ls[10], ls[11]);
  }
  __syncthreads();

  // rank-count merge: wave w handles rows w*4..w*4+3; lane owns entries {lane+64c}.
  // Keys unique -> ranks 0..191 a permutation -> all 24 candbuf slots written.
#pragma unroll
  for (int rr = 0; rr < 4; ++rr) {
    const int row = w * 4 + rr;
    unsigned mine[3]; int rk[3] = {0, 0, 0};
#pragma unroll
    for (int c = 0; c < 3; ++c) mine[c] = sEnt[row][lane + 64 * c];
    for (int i4 = 0; i4 < NENT / 4; ++i4) {
      uint4 e = *(const uint4*)&sEnt[row][i4 * 4];
#pragma unroll
      for (int c = 0; c < 3; ++c) {
        rk[c] += (e.x > mine[c]) ? 1 : 0;
        rk[c] += (e.y > mine[c]) ? 1 : 0;
        rk[c] += (e.z > mine[c]) ? 1 : 0;
        rk[c] += (e.w > mine[c]) ? 1 : 0;
      }
    }
#pragma unroll
    for (int c = 0; c < 3; ++c) {
      if (rk[c] < TCAND) {
        unsigned low = mine[c] & 0x7FFu;
        int kcls = (int)(low >> 7);
        int loc = 127 - (int)(low & 127u);
        unsigned id = (unsigned)(hoff + (kcls >> 2) * 512 + (loc >> 4) * 64 +
                                 ((loc >> 2) & 3) * 16 + (kcls & 3) * 4 + (loc & 3));
        candbuf[(size_t)(b * NN + nbase + row) * 48 + half * 24 + rk[c]] = id;
      }
    }
  }
}

// ---------------- kernel 3: FUSED exact f64 top-20 + BN statistics ----------------
// 512 thr = 8 waves, 8 rows/block, grid PTS/8, XCD-swizzled (b=blk&3).
__global__ __launch_bounds__(512) void k_selstats(
    const unsigned* __restrict__ candbuf, const float* __restrict__ xT,
    const float* __restrict__ yG, const float* __restrict__ yC,
    int* __restrict__ idxout, double* __restrict__ stats) {
  __shared__ int sTop[8][KK];
  __shared__ float rs1[8][32], rs2[8][32];
  const int t = threadIdx.x, lane = t & 63, w = t >> 6;
  const int b = blockIdx.x & 3;
  const int n = (blockIdx.x >> 2) * 8 + w;
  const int row = b * NN + n;
  const unsigned* cp = candbuf + (size_t)row * 48;
  const int hf = lane & 1;
  unsigned long long k0, k1; int c0, c1;
#pragma unroll
  for (int pass = 0; pass < 2; ++pass) {
    const int ci = pass * 24 + ((lane < 48) ? (lane >> 1) : 23);
    const int mycand = (int)cp[ci];
    const float* xm = xT + ((size_t)b * NN + mycand) * CC + hf * 48;
    const float* xr = xT + ((size_t)b * NN + n) * CC + hf * 48;
    double dot = 0.0, m2 = 0.0;
#pragma unroll 4
    for (int j = 0; j < 12; ++j) {
      float4 a = *(const float4*)&xm[j * 4];
      float4 q = *(const float4*)&xr[j * 4];
      dot = fma((double)q.x, (double)a.x, dot); m2 = fma((double)a.x, (double)a.x, m2);
      dot = fma((double)q.y, (double)a.y, dot); m2 = fma((double)a.y, (double)a.y, m2);
      dot = fma((double)q.z, (double)a.z, dot); m2 = fma((double)a.z, (double)a.z, m2);
      dot = fma((double)q.w, (double)a.w, dot); m2 = fma((double)a.w, (double)a.w, m2);
    }
    dot += __shfl_xor(dot, 1);
    m2 += __shfl_xor(m2, 1);
    double sc = 2.0 * dot - m2;
    unsigned long long bits = (unsigned long long)__double_as_longlong(sc);
    bits ^= ((unsigned long long)((long long)bits >> 63)) | 0x8000000000000000ull;
    unsigned long long key = (bits & ~0xFFFull) | (unsigned long long)(4095 - mycand);
    if (pass == 0) { k0 = key; c0 = mycand; } else { k1 = key; c1 = mycand; }
  }
  int r0c = 0, r1c = 0;
#pragma unroll
  for (int j = 0; j < 24; ++j) {
    unsigned long long a = __shfl(k0, j * 2);
    unsigned long long bb = __shfl(k1, j * 2);
    r0c += (a > k0) ? 1 : 0; r0c += (bb > k0) ? 1 : 0;
    r1c += (a > k1) ? 1 : 0; r1c += (bb > k1) ? 1 : 0;
  }
  if (lane < 48 && hf == 0) {
    if (r0c < KK) { idxout[(size_t)row * KK + r0c] = c0; sTop[w][r0c] = c0; }
    if (r1c < KK) { idxout[(size_t)row * KK + r1c] = c1; sTop[w][r1c] = c1; }
  }
  __builtin_amdgcn_wave_barrier();  // same-wave LDS write->read fence (compile-time)

  // ---- phase B: norm statistics for this row ----
  const int o = lane & 31, kh = lane >> 5;
  const size_t cb = (size_t)row * 192 + o * 3;
  const float pc0 = yC[cb], pc1 = yC[cb + 1], pc2 = yC[cb + 2];
  float s1 = 0.f, s2 = 0.f;
#pragma unroll
  for (int j = 0; j < 10; ++j) {
    int m = sTop[w][2 * j + kh];
    size_t a = ((size_t)b * NN + m) * 192 + o * 3;
    float p0 = yG[a] + pc0, p1 = yG[a + 1] + pc1, p2 = yG[a + 2] + pc2;
    float nr = sqrtf(p0 * p0 + p1 * p1 + p2 * p2) + 1e-6f;
    s1 += nr; s2 = fmaf(nr, nr, s2);
  }
  s1 += __shfl_xor(s1, 32);
  s2 += __shfl_xor(s2, 32);
  if (lane < 32) { rs1[w][o] = s1; rs2[w][o] = s2; }
  __syncthreads();
  if (t < 32) {
    float a1 = 0.f, a2 = 0.f;
#pragma unroll
    for (int ww = 0; ww < 8; ++ww) { a1 += rs1[ww][t]; a2 += rs2[ww][t]; }
    atomicAdd(&stats[t], (double)a1);
    atomicAdd(&stats[32 + t], (double)a2);
  }
}

// ---------------- kernel 4: gather + activation + mean over k (BN inlined) ----------------
__global__ __launch_bounds__(256) void k_out(
    const float* __restrict__ yG, const float* __restrict__ yC,
    const int* __restrict__ idx, const double* __restrict__ stats,
    const float* __restrict__ gamma, const float* __restrict__ beta,
    float* __restrict__ out) {
  __shared__ float sS[64];
  const int t = threadIdx.x, o = t & 31, nl = t >> 5;
  if (t < 32) {
    const double M = (double)BB * NN * KK;
    double mean = stats[t] / M;
    double var = stats[32 + t] / M - mean * mean;
    double inv = 1.0 / sqrt(var + 1e-5);
    sS[t] = (float)((double)gamma[t] * inv);
    sS[32 + t] = (float)((double)beta[t] - mean * (double)gamma[t] * inv);
  }
  __syncthreads();
  const int b = blockIdx.x & 3;
  const int n = (blockIdx.x >> 2) * 8 + nl;
  const size_t cb = (size_t)(b * NN + n) * 192 + o * 3;
  const float pc0 = yC[cb], pc1 = yC[cb + 1], pc2 = yC[cb + 2];
  const float dc0 = yC[cb + 96], dc1 = yC[cb + 97], dc2 = yC[cb + 98];
  const float sc = sS[o], sh = sS[32 + o];
  const int* ip = idx + (size_t)(b * NN + n) * KK;
  float a0 = 0.f, a1 = 0.f, a2 = 0.f;
  for (int k = 0; k < KK; ++k) {
    int m = ip[k];
    size_t a = (size_t)(b * NN + m) * 192 + o * 3;
    float p0 = yG[a] + pc0, p1 = yG[a + 1] + pc1, p2 = yG[a + 2] + pc2;
    float d0 = yG[a + 96] + dc0, d1 = yG[a + 97] + dc1, d2 = yG[a + 98] + dc2;
    float nr = sqrtf(p0 * p0 + p1 * p1 + p2 * p2) + 1e-6f;
    float f = (sc * nr + sh) / nr;
    p0 *= f; p1 *= f; p2 *= f;
    float dt = p0 * d0 + p1 * d1 + p2 * d2;
    float w8 = (dt >= 0.f) ? 0.f : 0.8f * dt / (d0 * d0 + d1 * d1 + d2 * d2 + 1e-6f);
    a0 += p0 - w8 * d0; a1 += p1 - w8 * d1; a2 += p2 - w8 * d2;
  }
  const float inv = 1.f / (float)KK;
  const size_t ob = ((size_t)(b * OO + o) * 3) * NN + n;
  out[ob] = a0 * inv; out[ob + NN] = a1 * inv; out[ob + 2 * NN] = a2 * inv;
}

extern "C" void kernel_launch(void* const* d_in, const int* in_sizes, int n_in,
                              void* d_out, int out_size, void* d_ws, size_t ws_size,
                              hipStream_t stream) {
  (void)in_sizes; (void)n_in; (void)out_size;
  const float* x = (const float*)d_in[0];
  const float* Wf = (const float*)d_in[1];
  const float* Wd = (const float*)d_in[2];
  const float* gamma = (const float*)d_in[3];
  const float* beta = (const float*)d_in[4];
  float* out = (float*)d_out;

  char* ws = (char*)d_ws;
  size_t off = 0;
  auto alloc = [&](size_t bytes) -> void* {
    void* p = ws + off;
    off += (bytes + 255) & ~(size_t)255;
    return p;
  };
  float* yG = (float*)alloc((size_t)PTS * 192 * 4);
  float* yC = (float*)alloc((size_t)PTS * 192 * 4);
  float* xneg = (float*)alloc((size_t)PTS * 4);
  int* idx   = (int*)alloc((size_t)PTS * KK * 4);
  double* stats = (double*)alloc(64 * 8);
  unsigned short* hl = (unsigned short*)alloc((size_t)PTS * 192 * 2);
  float* xT  = (float*)alloc((size_t)PTS * CC * 4);
  unsigned* candbuf = (unsigned*)alloc((size_t)PTS * 48 * 4);
  if (ws_size < off) return;

  hipMemsetAsync(stats, 0, 64 * 8, stream);
  k_fp<<<dim3(PTS / 64), dim3(256), 0, stream>>>(x, Wf, Wd, yG, yC, xneg, hl, xT);
  k_dist<<<dim3(BB * NN / 16 * 2), dim3(256), 0, stream>>>(hl, xneg, candbuf);
  k_selstats<<<dim3(PTS / 8), dim3(512), 0, stream>>>(candbuf, xT, yG, yC, idx, stats);
  k_out<<<dim3(PTS / 8), dim3(256), 0, stream>>>(yG, yC, idx, stats, gamma, beta, out);
}

// Round 17
// 232.706 us; speedup vs baseline: 2.0382x; 1.3573x over previous
//
#include <hip/hip_runtime.h>

// Local context aggregation (DGCNN edge-conv style), MI355X.
// Pipeline (4 launches):
//   k_fp      : FUSED per-point pass: yG[n]=[F1|D1] (gather table, L2-fit/batch),
//               yC[n]=[Fc|Dc], xneg=-0.5|x|^2, bf16 hi table hb16[n][96], xT[n][96].
//   k_dist    : FUSED MFMA score + per-half top-24. R17: bf16-only coarse scoring
//               (error ~= the 20-bit key chop already proven safe; f64 refine rescues
//               order). Live set ~62 VGPR -> fits the allocator's preferred 64-reg tier
//               -> no remat (R9-R16: split-table live set ~100 never fit, 4x VALU bloat),
//               and 8 waves/SIMD occupancy becomes reachable.
//   k_selstats: FUSED f64 re-rank (top-20 -> idx) + BN norm statistics.
//   k_out     : BN scale/shift inlined + gather + directional leaky act + mean over k.
// ws usage: ~40 MB fixed.

namespace {
constexpr int BB = 4;
constexpr int NN = 4096;
constexpr int KK = 20;
constexpr int CC = 96;      // 32 features x 3 dims
constexpr int OO = 32;
constexpr int PTS = BB * NN;
constexpr int LT = 12;      // per-class top list depth (class = 128 cands)
constexpr int TCAND = 24;   // per-half candidates kept
constexpr int NENT = 16 * LT;     // entries per row: 4 waves x 4 kl x 12 = 192
constexpr int NENT_PAD = 196;     // padded row stride (words)
}

using bf16x8 = __attribute__((ext_vector_type(8))) short;
using f32x4 = __attribute__((ext_vector_type(4))) float;

__device__ __forceinline__ unsigned short f2bf(float f) {
  unsigned u = __float_as_uint(f);
  return (unsigned short)((u + 0x7fff + ((u >> 16) & 1)) >> 16);
}
__device__ __forceinline__ unsigned umax32(unsigned a, unsigned b) { return a > b ? a : b; }
__device__ __forceinline__ unsigned med3u(unsigned a, unsigned b, unsigned c) {
  unsigned d;
  asm("v_med3_u32 %0, %1, %2, %3" : "=v"(d) : "v"(a), "v"(b), "v"(c));
  return d;
}

// ---------------- kernel 1: fused per-point pass ----------------
__global__ __launch_bounds__(256) void k_fp(
    const float* __restrict__ x, const float* __restrict__ Wf,
    const float* __restrict__ Wd,
    float* __restrict__ yG, float* __restrict__ yC, float* __restrict__ xneg,
    unsigned short* __restrict__ hb16, float* __restrict__ xT) {
  __shared__ float tile[CC][65];   // ~25 KB
  __shared__ float sW[4][32][32];  // 16 KB
  const int t = threadIdx.x;
  const int b = blockIdx.x >> 6;             // 64 blocks per batch
  const int n0 = (blockIdx.x & 63) * 64;
  for (int i = t; i < 2048; i += 256) {
    int o = i & 31, f = (i >> 5) & 31, which = i >> 10;
    const float* W = which ? Wd : Wf;
    float a1 = W[o * 64 + f], a2 = W[o * 64 + 32 + f];
    sW[which * 2 + 0][f][o] = a1;
    sW[which * 2 + 1][f][o] = a2 - a1;
  }
#pragma unroll
  for (int i = 0; i < 24; ++i) {
    int v = i * 256 + t;
    int c = v >> 6, nn = v & 63;
    tile[c][nn] = x[((size_t)b * CC + c) * NN + n0 + nn];
  }
  __syncthreads();

  // ---- bf16 hi table: hb16 rows [96 bf16], 12 x 16B chunks per row ----
#pragma unroll
  for (int i = 0; i < 3; ++i) {
    int v = i * 256 + t;                    // 0..767 over 64 rows x 12 chunks
    int row = v / 12, k8 = v % 12;
    int c0 = k8 * 8;
    unsigned hb[4];
#pragma unroll
    for (int j = 0; j < 4; ++j) {
      unsigned short l16 = f2bf(tile[c0 + 2 * j][row]);
      unsigned short h16 = f2bf(tile[c0 + 2 * j + 1][row]);
      hb[j] = (unsigned)l16 | ((unsigned)h16 << 16);
    }
    *(uint4*)(hb16 + (size_t)(b * NN + n0 + row) * 96 + k8 * 8) =
        make_uint4(hb[0], hb[1], hb[2], hb[3]);
  }
  // xT rows: 96 f32 contiguous per point
#pragma unroll
  for (int i = 0; i < 6; ++i) {
    int v = i * 256 + t;
    int row = v / 24, q = v % 24;
    float4 o4;
    o4.x = tile[q * 4 + 0][row]; o4.y = tile[q * 4 + 1][row];
    o4.z = tile[q * 4 + 2][row]; o4.w = tile[q * 4 + 3][row];
    *(float4*)(xT + (size_t)(b * NN + n0 + row) * CC + q * 4) = o4;
  }

  // ---- transforms: thread (o=t&31, pg=t>>5) handles 8 points ----
  const int o = t & 31, pg = t >> 5;
  for (int pp = 0; pp < 8; ++pp) {
    const int pl = pg * 8 + pp;              // point 0..63
    float aF1[3] = {0.f, 0.f, 0.f}, aFc[3] = {0.f, 0.f, 0.f};
    float aD1[3] = {0.f, 0.f, 0.f}, aDc[3] = {0.f, 0.f, 0.f};
#pragma unroll
    for (int f = 0; f < 32; ++f) {
      float w0 = sW[0][f][o], w1 = sW[1][f][o];
      float w2 = sW[2][f][o], w3 = sW[3][f][o];
#pragma unroll
      for (int dd = 0; dd < 3; ++dd) {
        float v = tile[f * 3 + dd][pl];
        aF1[dd] = fmaf(w0, v, aF1[dd]);
        aFc[dd] = fmaf(w1, v, aFc[dd]);
        aD1[dd] = fmaf(w2, v, aD1[dd]);
        aDc[dd] = fmaf(w3, v, aDc[dd]);
      }
    }
    const size_t pt = (size_t)(b * NN + n0 + pl) * 192 + o * 3;
#pragma unroll
    for (int dd = 0; dd < 3; ++dd) {
      yG[pt + dd] = aF1[dd]; yG[pt + 96 + dd] = aD1[dd];
      yC[pt + dd] = aFc[dd]; yC[pt + 96 + dd] = aDc[dd];
    }
  }
  // xneg: one thread per point
  if (t < 64) {
    float s = 0.f;
#pragma unroll 8
    for (int c = 0; c < CC; ++c) { float v = tile[c][t]; s = fmaf(v, v, s); }
    xneg[b * NN + n0 + t] = -0.5f * s;
  }
}

// ---------------- kernel 2: FUSED MFMA score + per-half top-24 ----------------
// 2048 blocks x 256 thr (4 waves). xcd=wg&7: b=xcd&3, half=xcd>>2. q=wg>>3 -> 16 rows.
// Wave w scans [half*2048 + w*512, +512): flat 32-step loop, register double-buffer,
// bf16-only scoring (3 MFMA/tile, 4 loads/tile). Score = hi_n.hi_m - 0.5|x_m|^2;
// error ~0.03 ~= existing 20-bit key chop; f64 refine of the 48-union fixes order.
// key = monotone(score)[31:12] | class[10:7] | (127-local)[6:0]  (unique in block).
__global__ __launch_bounds__(256) void k_dist(
    const unsigned short* __restrict__ hl, const float* __restrict__ xneg,
    unsigned* __restrict__ candbuf) {
  __shared__ unsigned sEnt[16][NENT_PAD];
  const int t = threadIdx.x, lane = t & 63, w = t >> 6;
  const int wg = blockIdx.x;
  const int xcd = wg & 7;
  const int b = xcd & 3;
  const int half = xcd >> 2;
  const int nbase = (wg >> 3) << 4;          // 0..4080, step 16
  const int hoff = half * 2048;
  const int coff = hoff + w * 512;           // this wave's candidate range
  const unsigned short* hb = hl + (size_t)b * NN * 96;
  const int kl = lane >> 4, pr = lane & 15;
  const int cls = w * 4 + kl;                // 0..15
  const unsigned clsbase = (unsigned)(cls << 7);

  // resident operand-B fragments: the block's 16 query rows (col axis)
  bf16x8 rHf[3];
#pragma unroll
  for (int kb = 0; kb < 3; ++kb) {
    const unsigned short* p = hb + (size_t)(nbase + pr) * 96 + (kb * 4 + kl) * 8;
    rHf[kb] = *(const bf16x8*)p;
  }

  unsigned ls[LT];
#pragma unroll
  for (int j = 0; j < LT; ++j) ls[j] = 0u;   // 0 == -inf key

  // bases: candidate group idx (0..31) lives at pw + idx*1536 (shorts), xneg at px+idx*16
  const unsigned short* pw = hb + ((size_t)coff + pr) * 96 + (size_t)kl * 8;
  const float* px = xneg + (size_t)b * NN + coff + kl * 4;

  bf16x8 ch0, ch1, ch2;   // current fragment set
  f32x4 cxn;
  {
    ch0 = *(const bf16x8*)(pw);
    ch1 = *(const bf16x8*)(pw + 32);
    ch2 = *(const bf16x8*)(pw + 64);
    cxn = *(const f32x4*)(px);
  }
#pragma unroll
  for (int idx = 0; idx < 32; ++idx) {
    // prefetch next group (clamped tail)
    const int ni = (idx < 31) ? idx + 1 : 31;
    const unsigned short* pn = pw + (size_t)ni * 1536;
    bf16x8 nh0 = *(const bf16x8*)(pn);
    bf16x8 nh1 = *(const bf16x8*)(pn + 32);
    bf16x8 nh2 = *(const bf16x8*)(pn + 64);
    f32x4 nxn = *(const f32x4*)(px + ni * 16);
    // pin: prefetch loads above issued before the compute below
    __builtin_amdgcn_sched_barrier(0);

    f32x4 acc = cxn;                          // -0.5*|xm|^2 preloaded
    acc = __builtin_amdgcn_mfma_f32_16x16x32_bf16(ch0, rHf[0], acc, 0, 0, 0);
    acc = __builtin_amdgcn_mfma_f32_16x16x32_bf16(ch1, rHf[1], acc, 0, 0, 0);
    acc = __builtin_amdgcn_mfma_f32_16x16x32_bf16(ch2, rHf[2], acc, 0, 0, 0);
    // C/D: col(lane&15)=query row; row((lane>>4)*4+r)=candidate offset.
    const unsigned tag = clsbase | (unsigned)(127 - idx * 4);
#pragma unroll
    for (int r = 0; r < 4; ++r) {
      unsigned sb = __float_as_uint(acc[r]);
      sb ^= ((unsigned)((int)sb >> 31)) | 0x80000000u;
      unsigned key = (sb & 0xFFFFF000u) | (tag - (unsigned)r);
      // in-place parallel sorted-desc insert via med3 (reads pre-insert state)
#pragma unroll
      for (int j = LT - 1; j >= 1; --j)
        ls[j] = med3u(ls[j - 1], ls[j], key);
      ls[0] = umax32(ls[0], key);
    }
    // rotate buffers (free after full unroll: pure renaming)
    ch0 = nh0; ch1 = nh1; ch2 = nh2; cxn = nxn;
  }
  // dump per-lane sorted key lists: row pr, entries [cls*12 .. +12)
  {
    unsigned* dst = &sEnt[pr][cls * LT];
    *(uint4*)(dst + 0) = make_uint4(ls[0], ls[1], ls[2], ls[3]);
    *(uint4*)(dst + 4) = make_uint4(ls[4], ls[5], ls[6], ls[7]);
    *(uint4*)(dst + 8) = make_uint4(ls[8], ls[9], ls[10], ls[11]);
  }
  __syncthreads();

  // rank-count merge: wave w handles rows w*4..w*4+3; lane owns entries {lane+64c}.
  // Keys unique -> ranks 0..191 a permutation -> all 24 candbuf slots written.
#pragma unroll
  for (int rr = 0; rr < 4; ++rr) {
    const int row = w * 4 + rr;
    unsigned mine[3]; int rk[3] = {0, 0, 0};
#pragma unroll
    for (int c = 0; c < 3; ++c) mine[c] = sEnt[row][lane + 64 * c];
    for (int i4 = 0; i4 < NENT / 4; ++i4) {
      uint4 e = *(const uint4*)&sEnt[row][i4 * 4];
#pragma unroll
      for (int c = 0; c < 3; ++c) {
        rk[c] += (e.x > mine[c]) ? 1 : 0;
        rk[c] += (e.y > mine[c]) ? 1 : 0;
        rk[c] += (e.z > mine[c]) ? 1 : 0;
        rk[c] += (e.w > mine[c]) ? 1 : 0;
      }
    }
#pragma unroll
    for (int c = 0; c < 3; ++c) {
      if (rk[c] < TCAND) {
        unsigned low = mine[c] & 0x7FFu;
        int kcls = (int)(low >> 7);
        int loc = 127 - (int)(low & 127u);
        unsigned id = (unsigned)(hoff + (kcls >> 2) * 512 + (loc >> 4) * 64 +
                                 ((loc >> 2) & 3) * 16 + (kcls & 3) * 4 + (loc & 3));
        candbuf[(size_t)(b * NN + nbase + row) * 48 + half * 24 + rk[c]] = id;
      }
    }
  }
}

// ---------------- kernel 3: FUSED exact f64 top-20 + BN statistics ----------------
// 512 thr = 8 waves, 8 rows/block, grid PTS/8, XCD-swizzled (b=blk&3).
__global__ __launch_bounds__(512) void k_selstats(
    const unsigned* __restrict__ candbuf, const float* __restrict__ xT,
    const float* __restrict__ yG, const float* __restrict__ yC,
    int* __restrict__ idxout, double* __restrict__ stats) {
  __shared__ int sTop[8][KK];
  __shared__ float rs1[8][32], rs2[8][32];
  const int t = threadIdx.x, lane = t & 63, w = t >> 6;
  const int b = blockIdx.x & 3;
  const int n = (blockIdx.x >> 2) * 8 + w;
  const int row = b * NN + n;
  const unsigned* cp = candbuf + (size_t)row * 48;
  const int hf = lane & 1;
  unsigned long long k0, k1; int c0, c1;
#pragma unroll
  for (int pass = 0; pass < 2; ++pass) {
    const int ci = pass * 24 + ((lane < 48) ? (lane >> 1) : 23);
    const int mycand = (int)cp[ci];
    const float* xm = xT + ((size_t)b * NN + mycand) * CC + hf * 48;
    const float* xr = xT + ((size_t)b * NN + n) * CC + hf * 48;
    double dot = 0.0, m2 = 0.0;
#pragma unroll 4
    for (int j = 0; j < 12; ++j) {
      float4 a = *(const float4*)&xm[j * 4];
      float4 q = *(const float4*)&xr[j * 4];
      dot = fma((double)q.x, (double)a.x, dot); m2 = fma((double)a.x, (double)a.x, m2);
      dot = fma((double)q.y, (double)a.y, dot); m2 = fma((double)a.y, (double)a.y, m2);
      dot = fma((double)q.z, (double)a.z, dot); m2 = fma((double)a.z, (double)a.z, m2);
      dot = fma((double)q.w, (double)a.w, dot); m2 = fma((double)a.w, (double)a.w, m2);
    }
    dot += __shfl_xor(dot, 1);
    m2 += __shfl_xor(m2, 1);
    double sc = 2.0 * dot - m2;
    unsigned long long bits = (unsigned long long)__double_as_longlong(sc);
    bits ^= ((unsigned long long)((long long)bits >> 63)) | 0x8000000000000000ull;
    unsigned long long key = (bits & ~0xFFFull) | (unsigned long long)(4095 - mycand);
    if (pass == 0) { k0 = key; c0 = mycand; } else { k1 = key; c1 = mycand; }
  }
  int r0c = 0, r1c = 0;
#pragma unroll
  for (int j = 0; j < 24; ++j) {
    unsigned long long a = __shfl(k0, j * 2);
    unsigned long long bb = __shfl(k1, j * 2);
    r0c += (a > k0) ? 1 : 0; r0c += (bb > k0) ? 1 : 0;
    r1c += (a > k1) ? 1 : 0; r1c += (bb > k1) ? 1 : 0;
  }
  if (lane < 48 && hf == 0) {
    if (r0c < KK) { idxout[(size_t)row * KK + r0c] = c0; sTop[w][r0c] = c0; }
    if (r1c < KK) { idxout[(size_t)row * KK + r1c] = c1; sTop[w][r1c] = c1; }
  }
  __builtin_amdgcn_wave_barrier();  // same-wave LDS write->read fence (compile-time)

  // ---- phase B: norm statistics for this row ----
  const int o = lane & 31, kh = lane >> 5;
  const size_t cb = (size_t)row * 192 + o * 3;
  const float pc0 = yC[cb], pc1 = yC[cb + 1], pc2 = yC[cb + 2];
  float s1 = 0.f, s2 = 0.f;
#pragma unroll
  for (int j = 0; j < 10; ++j) {
    int m = sTop[w][2 * j + kh];
    size_t a = ((size_t)b * NN + m) * 192 + o * 3;
    float p0 = yG[a] + pc0, p1 = yG[a + 1] + pc1, p2 = yG[a + 2] + pc2;
    float nr = sqrtf(p0 * p0 + p1 * p1 + p2 * p2) + 1e-6f;
    s1 += nr; s2 = fmaf(nr, nr, s2);
  }
  s1 += __shfl_xor(s1, 32);
  s2 += __shfl_xor(s2, 32);
  if (lane < 32) { rs1[w][o] = s1; rs2[w][o] = s2; }
  __syncthreads();
  if (t < 32) {
    float a1 = 0.f, a2 = 0.f;
#pragma unroll
    for (int ww = 0; ww < 8; ++ww) { a1 += rs1[ww][t]; a2 += rs2[ww][t]; }
    atomicAdd(&stats[t], (double)a1);
    atomicAdd(&stats[32 + t], (double)a2);
  }
}

// ---------------- kernel 4: gather + activation + mean over k (BN inlined) ----------------
__global__ __launch_bounds__(256) void k_out(
    const float* __restrict__ yG, const float* __restrict__ yC,
    const int* __restrict__ idx, const double* __restrict__ stats,
    const float* __restrict__ gamma, const float* __restrict__ beta,
    float* __restrict__ out) {
  __shared__ float sS[64];
  const int t = threadIdx.x, o = t & 31, nl = t >> 5;
  if (t < 32) {
    const double M = (double)BB * NN * KK;
    double mean = stats[t] / M;
    double var = stats[32 + t] / M - mean * mean;
    double inv = 1.0 / sqrt(var + 1e-5);
    sS[t] = (float)((double)gamma[t] * inv);
    sS[32 + t] = (float)((double)beta[t] - mean * (double)gamma[t] * inv);
  }
  __syncthreads();
  const int b = blockIdx.x & 3;
  const int n = (blockIdx.x >> 2) * 8 + nl;
  const size_t cb = (size_t)(b * NN + n) * 192 + o * 3;
  const float pc0 = yC[cb], pc1 = yC[cb + 1], pc2 = yC[cb + 2];
  const float dc0 = yC[cb + 96], dc1 = yC[cb + 97], dc2 = yC[cb + 98];
  const float sc = sS[o], sh = sS[32 + o];
  const int* ip = idx + (size_t)(b * NN + n) * KK;
  float a0 = 0.f, a1 = 0.f, a2 = 0.f;
  for (int k = 0; k < KK; ++k) {
    int m = ip[k];
    size_t a = (size_t)(b * NN + m) * 192 + o * 3;
    float p0 = yG[a] + pc0, p1 = yG[a + 1] + pc1, p2 = yG[a + 2] + pc2;
    float d0 = yG[a + 96] + dc0, d1 = yG[a + 97] + dc1, d2 = yG[a + 98] + dc2;
    float nr = sqrtf(p0 * p0 + p1 * p1 + p2 * p2) + 1e-6f;
    float f = (sc * nr + sh) / nr;
    p0 *= f; p1 *= f; p2 *= f;
    float dt = p0 * d0 + p1 * d1 + p2 * d2;
    float w8 = (dt >= 0.f) ? 0.f : 0.8f * dt / (d0 * d0 + d1 * d1 + d2 * d2 + 1e-6f);
    a0 += p0 - w8 * d0; a1 += p1 - w8 * d1; a2 += p2 - w8 * d2;
  }
  const float inv = 1.f / (float)KK;
  const size_t ob = ((size_t)(b * OO + o) * 3) * NN + n;
  out[ob] = a0 * inv; out[ob + NN] = a1 * inv; out[ob + 2 * NN] = a2 * inv;
}

extern "C" void kernel_launch(void* const* d_in, const int* in_sizes, int n_in,
                              void* d_out, int out_size, void* d_ws, size_t ws_size,
                              hipStream_t stream) {
  (void)in_sizes; (void)n_in; (void)out_size;
  const float* x = (const float*)d_in[0];
  const float* Wf = (const float*)d_in[1];
  const float* Wd = (const float*)d_in[2];
  const float* gamma = (const float*)d_in[3];
  const float* beta = (const float*)d_in[4];
  float* out = (float*)d_out;

  char* ws = (char*)d_ws;
  size_t off = 0;
  auto alloc = [&](size_t bytes) -> void* {
    void* p = ws + off;
    off += (bytes + 255) & ~(size_t)255;
    return p;
  };
  float* yG = (float*)alloc((size_t)PTS * 192 * 4);
  float* yC = (float*)alloc((size_t)PTS * 192 * 4);
  float* xneg = (float*)alloc((size_t)PTS * 4);
  int* idx   = (int*)alloc((size_t)PTS * KK * 4);
  double* stats = (double*)alloc(64 * 8);
  unsigned short* hb16 = (unsigned short*)alloc((size_t)PTS * 96 * 2);
  float* xT  = (float*)alloc((size_t)PTS * CC * 4);
  unsigned* candbuf = (unsigned*)alloc((size_t)PTS * 48 * 4);
  if (ws_size < off) return;

  hipMemsetAsync(stats, 0, 64 * 8, stream);
  k_fp<<<dim3(PTS / 64), dim3(256), 0, stream>>>(x, Wf, Wd, yG, yC, xneg, hb16, xT);
  k_dist<<<dim3(BB * NN / 16 * 2), dim3(256), 0, stream>>>(hb16, xneg, candbuf);
  k_selstats<<<dim3(PTS / 8), dim3(512), 0, stream>>>(candbuf, xT, yG, yC, idx, stats);
  k_out<<<dim3(PTS / 8), dim3(256), 0, stream>>>(yG, yC, idx, stats, gamma, beta, out);
}